// Round 9
// baseline (787.742 us; speedup 1.0000x reference)
//
#include <hip/hip_runtime.h>
#include <hip/hip_bf16.h>
#include <stdint.h>
#include <stddef.h>

#define N_NODES 100000
#define N_EDGES 1600000
#define FEAT 128
#define NB_SCAN ((N_NODES + 255) / 256)   // 391 blocks of 256 for the scan
#define LDS_PITCH 136                     // u16; 272 B/row: uniform bank spread for b128
#define CAP 24                            // edges per gather chunk
#define NL (CAP / 4)                      // 6 load instructions per chunk
#define NBKT ((N_NODES + 255) / 256)      // 391 row-buckets of 256 rows
#define BCAP 8160                         // slots per bucket (mean 4096, +63 sigma)
#define EPB 2048                          // edges per phase-1 block (782 blocks, ~3/CU)

typedef __attribute__((ext_vector_type(8))) short bf16x8;
typedef __attribute__((ext_vector_type(4))) float f32x4;
typedef unsigned short u16;

__device__ __forceinline__ float bf2f(u16 u) {
    union { unsigned int i; float f; } v; v.i = ((unsigned int)u) << 16; return v.f;
}
__device__ __forceinline__ u16 f2bf(float f) {
    union { float f; unsigned int i; } v; v.f = f;
    unsigned int x = v.i;
    return (u16)((x + 0x7fffu + ((x >> 16) & 1u)) >> 16);   // round-nearest-even
}

// ---------------- CSR build: legacy kernels (fallback path) ----------------

__global__ void hist_kernel(const int* __restrict__ rows, int* __restrict__ counts) {
    int e = blockIdx.x * blockDim.x + threadIdx.x;
    if (e < N_EDGES) {
        int r = rows[e];
        r = min(max(r, 0), N_NODES - 1);
        atomicAdd(&counts[r], 1);
    }
}

__global__ void reduce_counts_kernel(const int* __restrict__ counts, int* __restrict__ bsum) {
    __shared__ int s[256];
    int i = blockIdx.x * 256 + threadIdx.x;
    int v = (i < N_NODES) ? counts[i] : 0;
    s[threadIdx.x] = v; __syncthreads();
    for (int off = 128; off > 0; off >>= 1) {
        if (threadIdx.x < off) s[threadIdx.x] += s[threadIdx.x + off];
        __syncthreads();
    }
    if (threadIdx.x == 0) bsum[blockIdx.x] = s[0];
}

__global__ void scan_bsums_kernel(int* __restrict__ bsum, int* __restrict__ row_ptr) {
    __shared__ int s[512];
    int t = threadIdx.x;
    int v = (t < NB_SCAN) ? bsum[t] : 0;
    s[t] = v; __syncthreads();
    for (int off = 1; off < 512; off <<= 1) {
        int x = (t >= off) ? s[t - off] : 0;
        __syncthreads();
        s[t] += x;
        __syncthreads();
    }
    if (t < NB_SCAN) bsum[t] = s[t] - v;              // exclusive
    if (t == NB_SCAN - 1) row_ptr[N_NODES] = s[t];    // total (= N_EDGES)
}

// also zeroes counts so it can be reused as the scatter fill array
__global__ void write_rowptr_kernel(int* __restrict__ counts, const int* __restrict__ bsum,
                                    int* __restrict__ row_ptr) {
    __shared__ int s[256];
    int i = blockIdx.x * 256 + threadIdx.x;
    int v = (i < N_NODES) ? counts[i] : 0;
    s[threadIdx.x] = v; __syncthreads();
    for (int off = 1; off < 256; off <<= 1) {
        int x = (threadIdx.x >= off) ? s[threadIdx.x - off] : 0;
        __syncthreads();
        s[threadIdx.x] += x;
        __syncthreads();
    }
    if (i < N_NODES) {
        row_ptr[i] = bsum[blockIdx.x] + s[threadIdx.x] - v;  // exclusive
        counts[i] = 0;                                       // becomes fill[]
    }
}

// legacy random scatter (fallback path only)
__global__ void scatter_kernel(const int* __restrict__ rows, const int* __restrict__ cols,
                               const float* __restrict__ w, const int* __restrict__ row_ptr,
                               int* __restrict__ fill, int2* __restrict__ ecw) {
    int e = blockIdx.x * blockDim.x + threadIdx.x;
    if (e < N_EDGES) {
        int r = rows[e];
        r = min(max(r, 0), N_NODES - 1);
        int pos = row_ptr[r] + atomicAdd(&fill[r], 1);
        pos = min(max(pos, 0), N_EDGES - 1);
        int c = cols[e];
        c = min(max(c, 0), N_NODES - 1);
        ecw[pos] = make_int2(c, __float_as_int(w[e]));
    }
}

// ---------------- CSR build v2: bucketed, write-merged ---------------------

__global__ __launch_bounds__(256) void bucket_p1_kernel(const int* __restrict__ rows,
                                                        const int* __restrict__ cols,
                                                        const float* __restrict__ w,
                                                        int* __restrict__ gcnt,
                                                        int2* __restrict__ bbuf) {
    __shared__ int s_cnt[NBKT];
    __shared__ int s_base[NBKT];
    int tid = threadIdx.x;
    for (int b = tid; b < NBKT; b += 256) s_cnt[b] = 0;
    __syncthreads();
    int e0 = blockIdx.x * EPB;
#pragma unroll
    for (int it = 0; it < EPB / 256; ++it) {
        int e = e0 + it * 256 + tid;
        if (e < N_EDGES) {
            int r = min(max(rows[e], 0), N_NODES - 1);
            atomicAdd(&s_cnt[r >> 8], 1);
        }
    }
    __syncthreads();
    for (int b = tid; b < NBKT; b += 256) {
        s_base[b] = atomicAdd(&gcnt[b], s_cnt[b]);
        s_cnt[b] = 0;
    }
    __syncthreads();
#pragma unroll
    for (int it = 0; it < EPB / 256; ++it) {
        int e = e0 + it * 256 + tid;
        if (e < N_EDGES) {
            int r = min(max(rows[e], 0), N_NODES - 1);
            int b = r >> 8;
            int k = atomicAdd(&s_cnt[b], 1);
            int pos = min(s_base[b] + k, BCAP - 1);          // statistically impossible clamp
            int c = min(max(cols[e], 0), N_NODES - 1);
            bbuf[(size_t)b * BCAP + pos] = make_int2(c | ((r & 255) << 20), __float_as_int(w[e]));
        }
    }
}

// Phase 2a: one block per bucket -> per-row counts via LDS atomics
__global__ __launch_bounds__(256) void bucket_count_kernel(const int* __restrict__ gcnt,
                                                           const int2* __restrict__ bbuf,
                                                           int* __restrict__ counts) {
    __shared__ int s_cnt[256];
    int b = blockIdx.x, tid = threadIdx.x;
    s_cnt[tid] = 0; __syncthreads();
    int cnt = min(gcnt[b], BCAP);
    for (int i = tid; i < cnt; i += 256)
        atomicAdd(&s_cnt[bbuf[(size_t)b * BCAP + i].x >> 20], 1);
    __syncthreads();
    int r = b * 256 + tid;
    if (r < N_NODES) counts[r] = s_cnt[tid];
}

// Phase 2b: one block per bucket, fill counters in LDS, write-merged scatter
__global__ __launch_bounds__(256) void bucket_scatter_kernel(const int* __restrict__ gcnt,
                                                             const int2* __restrict__ bbuf,
                                                             const int* __restrict__ row_ptr,
                                                             int2* __restrict__ ecw) {
    __shared__ int s_fill[256];
    int b = blockIdx.x, tid = threadIdx.x;
    s_fill[tid] = 0; __syncthreads();
    int cnt = min(gcnt[b], BCAP);
    for (int i = tid; i < cnt; i += 256) {
        int2 p = bbuf[(size_t)b * BCAP + i];
        int rl = p.x >> 20;
        int r = b * 256 + rl;
        int pos = row_ptr[r] + atomicAdd(&s_fill[rl], 1);
        pos = min(max(pos, 0), N_EDGES - 1);
        ecw[pos] = make_int2(p.x & 0xFFFFF, p.y);
    }
}

// -------- weight prep ------------------------------------------------------
__device__ __forceinline__ float w_fold(const float* W, int o, int k) {
    if (k < 128)      return W[o * 384 + k] - W[o * 384 + 256 + k];
    else if (k < 256) return W[o * 384 + k];
    else              return 2.0f * W[o * 384 + k];
}

__global__ void prep_w_kernel(const float* __restrict__ W, u16* __restrict__ Wp, int O) {
    int i = blockIdx.x * blockDim.x + threadIdx.x;
    if (i >= O * 384) return;
    int o = i / 384, k = i % 384;
    Wp[i] = f2bf(w_fold(W, o, k));
}

// MFMA-fragment-packed W' (for the streaming gemm)
__global__ void prep_w2_kernel(const float* __restrict__ W, u16* __restrict__ Wp2, int O) {
    int i = blockIdx.x * blockDim.x + threadIdx.x;
    int total = (O / 16) * 12 * 64;
    if (i >= total) return;
    int ot = i / 768;            // 12*64
    int rem = i % 768;
    int kk = rem / 64;
    int l = rem % 64;
    int q = l >> 4, r = l & 15;
    int o = ot * 16 + r;
    int kbase = kk * 32 + q * 8;
#pragma unroll
    for (int j = 0; j < 8; ++j)
        Wp2[(size_t)i * 8 + j] = f2bf(w_fold(W, o, kbase + j));
}

// -------- x (f32) -> bf16, 4 elems per thread ----------

__global__ void cvt_kernel(const float* __restrict__ x, u16* __restrict__ y) {
    int i = blockIdx.x * blockDim.x + threadIdx.x;
    if (i >= N_NODES * FEAT / 4) return;
    float4 v = ((const float4*)x)[i];
    ushort4 o;
    o.x = f2bf(v.x); o.y = f2bf(v.y); o.z = f2bf(v.z); o.w = f2bf(v.w);
    ((ushort4*)y)[i] = o;
}

// -------- branch-free register gather primitives --------------------------

__device__ __forceinline__ void load_meta(const int2* __restrict__ ecw, int s, int n,
                                          int lane, int& call, float& wall) {
    int idx = s + max(0, min(lane, n - 1));       // clamp: branch-free
    idx = min(idx, N_EDGES - 1);                  // deg-0 last-row guard
    int2 cw = ecw[idx];
    call = cw.x;
    wall = (lane < n) ? __int_as_float(cw.y) : 0.f;   // cndmask, no branch
}

__device__ __forceinline__ void issue_row(const u16* __restrict__ X, int call,
                                          int g, int f, bf16x8* q) {
#pragma unroll
    for (int k = 0; k < NL; ++k) {
        int col = __shfl(call, k * 4 + g);
        q[k] = *(const bf16x8*)(X + (size_t)col * FEAT + f * 8);
    }
}

__device__ __forceinline__ void reduce_row(const bf16x8* q, float wall,
                                           int g, float* acc) {
#pragma unroll
    for (int k = 0; k < NL; ++k) {
        float wj = __shfl(wall, k * 4 + g);
#pragma unroll
        for (int j = 0; j < 8; ++j) acc[j] += wj * bf2f((u16)q[k][j]);
    }
}

// -------- SpMM v4: TWO ROWS PER WAVE, both issued before either reduce ----
// Probe: deep (12 loads in flight) AND wide (high occupancy). If BW stays
// at ~3.75 TB/s this confirms the per-CU miss-tracking cap.

__global__ __launch_bounds__(256) void spmm2_kernel(const int* __restrict__ row_ptr,
                                                    const int2* __restrict__ ecw,
                                                    const u16* __restrict__ X,
                                                    u16* __restrict__ Y) {
    int lane = threadIdx.x & 63;
    int g = lane >> 4, f = lane & 15;
    int r0 = ((blockIdx.x * blockDim.x + threadIdx.x) >> 6) * 2;   // 2 rows/wave

    int s0 = row_ptr[r0], m = row_ptr[r0 + 1], e1 = row_ptr[r0 + 2];
    float acc0[8], acc1[8];
#pragma unroll
    for (int j = 0; j < 8; ++j) { acc0[j] = 0.f; acc1[j] = 0.f; }

    int call0, call1; float wall0, wall1;
    load_meta(ecw, s0, min(m - s0, CAP), lane, call0, wall0);
    load_meta(ecw, m, min(e1 - m, CAP), lane, call1, wall1);
    bf16x8 q0[NL], q1[NL];
    issue_row(X, call0, g, f, q0);
    issue_row(X, call1, g, f, q1);       // 12 loads in flight before first use
    reduce_row(q0, wall0, g, acc0);
    reduce_row(q1, wall1, g, acc1);

    for (int cs = s0 + CAP; cs < m; cs += CAP) {     // rare tails (deg > 24)
        int c2; float w2;
        load_meta(ecw, cs, min(m - cs, CAP), lane, c2, w2);
        bf16x8 qt[NL];
        issue_row(X, c2, g, f, qt);
        reduce_row(qt, w2, g, acc0);
    }
    for (int cs = m + CAP; cs < e1; cs += CAP) {
        int c2; float w2;
        load_meta(ecw, cs, min(e1 - cs, CAP), lane, c2, w2);
        bf16x8 qt[NL];
        issue_row(X, c2, g, f, qt);
        reduce_row(qt, w2, g, acc1);
    }

#pragma unroll
    for (int j = 0; j < 8; ++j) {
        acc0[j] += __shfl_xor(acc0[j], 16);
        acc0[j] += __shfl_xor(acc0[j], 32);
        acc1[j] += __shfl_xor(acc1[j], 16);
        acc1[j] += __shfl_xor(acc1[j], 32);
    }
    // after fold both accs are replicated across g: g==0 stores row0, g==1 row1
    if (g == 0) {
        u16 tmp[8];
#pragma unroll
        for (int j = 0; j < 8; ++j) tmp[j] = f2bf(acc0[j]);
        *(bf16x8*)(Y + (size_t)r0 * FEAT + f * 8) = *(const bf16x8*)tmp;
    } else if (g == 1) {
        u16 tmp[8];
#pragma unroll
        for (int j = 0; j < 8; ++j) tmp[j] = f2bf(acc1[j]);
        *(bf16x8*)(Y + (size_t)(r0 + 1) * FEAT + f * 8) = *(const bf16x8*)tmp;
    }
}

// -------- gather4 (fallback fused path only) ------------------------------

__device__ __forceinline__ void gather4(const int* __restrict__ row_ptr,
                                        const int2* __restrict__ ecw,
                                        const u16* __restrict__ X,
                                        int r0, int lane, int g, int f,
                                        float acc[4][8]) {
    int s[4], e[4];
    int call[4]; float wall[4];
#pragma unroll
    for (int y = 0; y < 4; ++y) {
        s[y] = row_ptr[r0 + y];
        e[y] = row_ptr[r0 + y + 1];
    }
#pragma unroll
    for (int y = 0; y < 4; ++y)
        load_meta(ecw, s[y], min(e[y] - s[y], CAP), lane, call[y], wall[y]);
#pragma unroll
    for (int y = 0; y < 4; ++y)
#pragma unroll
        for (int j = 0; j < 8; ++j) acc[y][j] = 0.f;

    bf16x8 q0[NL], q1[NL], q2[NL], q3[NL];
    issue_row(X, call[0], g, f, q0);
    issue_row(X, call[1], g, f, q1);
    reduce_row(q0, wall[0], g, acc[0]);
    issue_row(X, call[2], g, f, q2);
    reduce_row(q1, wall[1], g, acc[1]);
    issue_row(X, call[3], g, f, q3);
    reduce_row(q2, wall[2], g, acc[2]);
    reduce_row(q3, wall[3], g, acc[3]);

#pragma unroll
    for (int y = 0; y < 4; ++y) {
        for (int cs = s[y] + CAP; cs < e[y]; cs += CAP) {
            int c2; float w2;
            load_meta(ecw, cs, min(e[y] - cs, CAP), lane, c2, w2);
            bf16x8 qt[NL];
            issue_row(X, c2, g, f, qt);
            reduce_row(qt, w2, g, acc[y]);
        }
    }

#pragma unroll
    for (int y = 0; y < 4; ++y)
#pragma unroll
        for (int j = 0; j < 8; ++j) {
            acc[y][j] += __shfl_xor(acc[y][j], 16);
            acc[y][j] += __shfl_xor(acc[y][j], 32);
        }
}

// legacy 4-rows-per-wave spmm (fallback path)
__global__ __launch_bounds__(256) void spmm_kernel(const int* __restrict__ row_ptr,
                                                   const int2* __restrict__ ecw,
                                                   const u16* __restrict__ X,
                                                   u16* __restrict__ Y) {
    int wid = threadIdx.x >> 6;
    int lane = threadIdx.x & 63;
    int g = lane >> 4, f = lane & 15;
    int r0 = blockIdx.x * 16 + wid * 4;

    float acc[4][8];
    gather4(row_ptr, ecw, X, r0, lane, g, f, acc);

    if (g == 0) {
#pragma unroll
        for (int y = 0; y < 4; ++y) {
            u16 tmp[8];
#pragma unroll
            for (int j = 0; j < 8; ++j) tmp[j] = f2bf(acc[y][j]);
            *(bf16x8*)(Y + (size_t)(r0 + y) * FEAT + f * 8) = *(const bf16x8*)tmp;
        }
    }
}

// ------- streaming GEMM v3: 64-row M-tile. Halves Wp2 L2 traffic, 4x MFMA
//         reuse per B-fragment. Tail block (100000 % 64 = 32) handled by
//         clamp-on-stage / guard-on-store.

template <int O, bool RELU, bool RES, bool OUT_F32>
__global__ __launch_bounds__(256) void gemm_kernel(const u16* __restrict__ H,
                                                   const u16* __restrict__ T1,
                                                   const u16* __restrict__ S2,
                                                   const u16* __restrict__ Wp2,
                                                   const float* __restrict__ bias,
                                                   void* __restrict__ outv) {
    __shared__ __align__(16) u16 sA[3][64][LDS_PITCH];    // 52.2 KB
    int tid = threadIdx.x;
    int m0 = blockIdx.x * 64;

    // stage 3 planes x 64 rows x 256B, coalesced 4KB per instruction
#pragma unroll
    for (int p = 0; p < 3; ++p) {
        const u16* sp = (p == 0) ? H : (p == 1) ? T1 : S2;
#pragma unroll
        for (int u = 0; u < 4; ++u) {
            int unit = u * 256 + tid;                     // 1024 units of 16B
            int row = unit >> 4, seg = unit & 15;
            int srow = min(m0 + row, N_NODES - 1);        // tail clamp
            *(bf16x8*)&sA[p][row][seg * 8] =
                *(const bf16x8*)(sp + (size_t)srow * FEAT + seg * 8);
        }
    }
    __syncthreads();

    int lane = tid & 63, wid = tid >> 6;
    int r = lane & 15, q = lane >> 4;
    constexpr int NW = O / 64;          // 2 for O=128, 1 for O=64
    f32x4 acc[NW][4];
#pragma unroll
    for (int t = 0; t < NW; ++t)
#pragma unroll
        for (int sub = 0; sub < 4; ++sub)
            acc[t][sub] = (f32x4){0.f, 0.f, 0.f, 0.f};

#pragma unroll
    for (int kk = 0; kk < 12; ++kk) {
        int p = kk >> 2, ko = kk & 3;
        bf16x8 af[4];
#pragma unroll
        for (int sub = 0; sub < 4; ++sub)
            af[sub] = *(const bf16x8*)&sA[p][sub * 16 + r][ko * 32 + q * 8];
#pragma unroll
        for (int t = 0; t < NW; ++t) {
            int ot = wid * NW + t;
            bf16x8 bfr = *(const bf16x8*)(Wp2 + ((size_t)(ot * 12 + kk) * 64 + lane) * 8);
#pragma unroll
            for (int sub = 0; sub < 4; ++sub)
                acc[t][sub] = __builtin_amdgcn_mfma_f32_16x16x32_bf16(af[sub], bfr, acc[t][sub], 0, 0, 0);
        }
    }

#pragma unroll
    for (int t = 0; t < NW; ++t) {
        int col = (wid * NW + t) * 16 + r;
        float bv = bias[col];
#pragma unroll
        for (int sub = 0; sub < 4; ++sub) {
#pragma unroll
            for (int i = 0; i < 4; ++i) {
                int lrow = sub * 16 + q * 4 + i;
                int row = m0 + lrow;
                if (row < N_NODES) {                      // tail guard
                    float v = acc[t][sub][i] + bv;
                    if (RES)  v += bf2f(sA[0][lrow][col]);
                    if (RELU) v = fmaxf(v, 0.f);
                    if (OUT_F32) ((float*)outv)[(size_t)row * O + col] = v;
                    else         ((u16*)outv)[(size_t)row * O + col] = f2bf(v);
                }
            }
        }
    }
}

// ------- fallback fused kernel (ws too small for s2): proven r2 path --------

template <int O, bool RELU, bool RES, bool OUT_F32>
__global__ __launch_bounds__(256) void fused_gemm_kernel(const int* __restrict__ row_ptr,
                                                         const int2* __restrict__ ecw,
                                                         const u16* __restrict__ H,
                                                         const u16* __restrict__ T1,
                                                         const u16* __restrict__ Wp,
                                                         const float* __restrict__ bias,
                                                         void* __restrict__ outv) {
    __shared__ __align__(16) u16 sT[16 * LDS_PITCH];
    int wid = threadIdx.x >> 6;
    int lane = threadIdx.x & 63;
    int g = lane >> 4, f = lane & 15;
    int m0 = blockIdx.x * 16;

    {
        float acc[4][8];
        gather4(row_ptr, ecw, T1, m0 + wid * 4, lane, g, f, acc);
        if (g == 0) {
#pragma unroll
            for (int y = 0; y < 4; ++y) {
                u16 tmp[8];
#pragma unroll
                for (int j = 0; j < 8; ++j) tmp[j] = f2bf(acc[y][j]);
                *(bf16x8*)(sT + (wid * 4 + y) * LDS_PITCH + f * 8) = *(const bf16x8*)tmp;
            }
        }
    }
    __syncthreads();

    int r = f, q = g;
    constexpr int NT = O / 16;
    constexpr int NW = NT / 4;
    f32x4 acc[NW];
#pragma unroll
    for (int t = 0; t < NW; ++t) acc[t] = (f32x4){0.f, 0.f, 0.f, 0.f};

#pragma unroll
    for (int kk = 0; kk < 12; ++kk) {
        bf16x8 af;
        if (kk < 4)
            af = *(const bf16x8*)(H + (size_t)(m0 + r) * FEAT + kk * 32 + q * 8);
        else if (kk < 8)
            af = *(const bf16x8*)(T1 + (size_t)(m0 + r) * FEAT + (kk - 4) * 32 + q * 8);
        else
            af = *(const bf16x8*)(sT + r * LDS_PITCH + (kk - 8) * 32 + q * 8);
#pragma unroll
        for (int t = 0; t < NW; ++t) {
            int ot = wid * NW + t;
            bf16x8 bfr = *(const bf16x8*)(Wp + (size_t)(ot * 16 + r) * 384 + kk * 32 + q * 8);
            acc[t] = __builtin_amdgcn_mfma_f32_16x16x32_bf16(af, bfr, acc[t], 0, 0, 0);
        }
    }

#pragma unroll
    for (int t = 0; t < NW; ++t) {
        int col = (wid * NW + t) * 16 + r;
        float bv = bias[col];
#pragma unroll
        for (int i = 0; i < 4; ++i) {
            int row = m0 + q * 4 + i;
            float v = acc[t][i] + bv;
            if (RES)  v += bf2f(H[(size_t)row * FEAT + col]);
            if (RELU) v = fmaxf(v, 0.f);
            if (OUT_F32) ((float*)outv)[(size_t)row * O + col] = v;
            else         ((u16*)outv)[(size_t)row * O + col] = f2bf(v);
        }
    }
}

// ---------------- launcher ----------------

static inline size_t align_up(size_t x) { return (x + 255) & ~(size_t)255; }

extern "C" void kernel_launch(void* const* d_in, const int* in_sizes, int n_in,
                              void* d_out, int out_size, void* d_ws, size_t ws_size,
                              hipStream_t stream) {
    const float* x     = (const float*)d_in[0];
    const int*   ei    = (const int*)d_in[1];
    const float* ew    = (const float*)d_in[2];
    const float* W_in  = (const float*)d_in[3];
    const float* b_in  = (const float*)d_in[4];
    const float* W_h1  = (const float*)d_in[5];
    const float* b_h1  = (const float*)d_in[6];
    const float* W_h2  = (const float*)d_in[7];
    const float* b_h2  = (const float*)d_in[8];
    const float* W_out = (const float*)d_in[9];
    const float* b_out = (const float*)d_in[10];

    const int* rows = ei;
    const int* cols = ei + N_EDGES;

    // workspace layout
    char* w = (char*)d_ws;
    size_t off = 0;
    int* counts = (int*)(w + off);            off = align_up(off + (size_t)N_NODES * 4);   // reused as fill
    int* row_ptr= (int*)(w + off);            off = align_up(off + (size_t)(N_NODES + 1) * 4);
    int* bsum   = (int*)(w + off);            off = align_up(off + 512 * 4);
    int2* ecw   = (int2*)(w + off);           off = align_up(off + (size_t)N_EDGES * 8);
    u16* t1     = (u16*)(w + off);            off = align_up(off + (size_t)N_NODES * FEAT * 2);
    u16* h      = (u16*)(w + off);            off = align_up(off + (size_t)N_NODES * FEAT * 2);
    u16* Wp_in  = (u16*)(w + off);            off = align_up(off + (size_t)128 * 384 * 2);
    u16* Wp_h1  = (u16*)(w + off);            off = align_up(off + (size_t)128 * 384 * 2);
    u16* Wp_h2  = (u16*)(w + off);            off = align_up(off + (size_t)128 * 384 * 2);
    u16* Wp_out = (u16*)(w + off);            off = align_up(off + (size_t)64 * 384 * 2);
    // split path: s2 buffer (+25.6 MB, doubles as the CSR bucket buffer),
    // fragment-packed weights, bucket counters
    u16* s2     = (u16*)(w + off);            size_t off2 = align_up(off + (size_t)N_NODES * FEAT * 2);
    u16* W2_in  = (u16*)(w + off2);           off2 = align_up(off2 + (size_t)128 * 384 * 2);
    u16* W2_h1  = (u16*)(w + off2);           off2 = align_up(off2 + (size_t)128 * 384 * 2);
    u16* W2_h2  = (u16*)(w + off2);           off2 = align_up(off2 + (size_t)128 * 384 * 2);
    u16* W2_out = (u16*)(w + off2);           off2 = align_up(off2 + (size_t)64 * 384 * 2);
    int* gcnt   = (int*)(w + off2);           off2 = align_up(off2 + (size_t)NBKT * 4);
    const bool use_split = (ws_size >= off2);
    static_assert((size_t)NBKT * BCAP * 8 <= (size_t)N_NODES * FEAT * 2, "bucket buffer exceeds s2");

    hipMemsetAsync(counts, 0, (size_t)N_NODES * 4, stream);

    cvt_kernel<<<(N_NODES * FEAT / 4 + 255) / 256, 256, 0, stream>>>(x, h);

    const int grid16 = N_NODES / 16;         // 6250 blocks (fallback)
    const int grid64 = (N_NODES + 63) / 64;  // 1563 blocks: 64-row gemm tiles
    const int grid2  = N_NODES / 2 * 64 / 256;   // 12500 blocks: 2 rows/wave

    if (use_split) {
        // CSR build v2: bucketed sort with write-merged scatter
        hipMemsetAsync(gcnt, 0, (size_t)NBKT * 4, stream);
        int2* bbuf = (int2*)s2;
        bucket_p1_kernel<<<(N_EDGES + EPB - 1) / EPB, 256, 0, stream>>>(rows, cols, ew, gcnt, bbuf);
        bucket_count_kernel<<<NBKT, 256, 0, stream>>>(gcnt, bbuf, counts);
        reduce_counts_kernel<<<NB_SCAN, 256, 0, stream>>>(counts, bsum);
        scan_bsums_kernel<<<1, 512, 0, stream>>>(bsum, row_ptr);
        write_rowptr_kernel<<<NB_SCAN, 256, 0, stream>>>(counts, bsum, row_ptr);
        bucket_scatter_kernel<<<NBKT, 256, 0, stream>>>(gcnt, bbuf, row_ptr, ecw);

        prep_w2_kernel<<<(128 * 384 / 8 + 255) / 256, 256, 0, stream>>>(W_in, W2_in, 128);
        prep_w2_kernel<<<(128 * 384 / 8 + 255) / 256, 256, 0, stream>>>(W_h1, W2_h1, 128);
        prep_w2_kernel<<<(128 * 384 / 8 + 255) / 256, 256, 0, stream>>>(W_h2, W2_h2, 128);
        prep_w2_kernel<<<(64 * 384 / 8 + 255) / 256, 256, 0, stream>>>(W_out, W2_out, 64);

        // Layer 1
        spmm2_kernel<<<grid2, 256, 0, stream>>>(row_ptr, ecw, h, t1);
        spmm2_kernel<<<grid2, 256, 0, stream>>>(row_ptr, ecw, t1, s2);
        gemm_kernel<128, true, false, false><<<grid64, 256, 0, stream>>>(h, t1, s2, W2_in, b_in, h);
        // Layer 2
        spmm2_kernel<<<grid2, 256, 0, stream>>>(row_ptr, ecw, h, t1);
        spmm2_kernel<<<grid2, 256, 0, stream>>>(row_ptr, ecw, t1, s2);
        gemm_kernel<128, true, true, false><<<grid64, 256, 0, stream>>>(h, t1, s2, W2_h1, b_h1, h);
        // Layer 3
        spmm2_kernel<<<grid2, 256, 0, stream>>>(row_ptr, ecw, h, t1);
        spmm2_kernel<<<grid2, 256, 0, stream>>>(row_ptr, ecw, t1, s2);
        gemm_kernel<128, true, true, false><<<grid64, 256, 0, stream>>>(h, t1, s2, W2_h2, b_h2, h);
        // Layer 4 (O=64, f32 out)
        spmm2_kernel<<<grid2, 256, 0, stream>>>(row_ptr, ecw, h, t1);
        spmm2_kernel<<<grid2, 256, 0, stream>>>(row_ptr, ecw, t1, s2);
        gemm_kernel<64, false, false, true><<<grid64, 256, 0, stream>>>(h, t1, s2, W2_out, b_out, d_out);
    } else {
        // fallback: legacy CSR build + fused path
        hist_kernel<<<N_EDGES / 256, 256, 0, stream>>>(rows, counts);
        reduce_counts_kernel<<<NB_SCAN, 256, 0, stream>>>(counts, bsum);
        scan_bsums_kernel<<<1, 512, 0, stream>>>(bsum, row_ptr);
        write_rowptr_kernel<<<NB_SCAN, 256, 0, stream>>>(counts, bsum, row_ptr);
        scatter_kernel<<<N_EDGES / 256, 256, 0, stream>>>(rows, cols, ew, row_ptr, counts, ecw);

        prep_w_kernel<<<(128 * 384 + 255) / 256, 256, 0, stream>>>(W_in, Wp_in, 128);
        prep_w_kernel<<<(128 * 384 + 255) / 256, 256, 0, stream>>>(W_h1, Wp_h1, 128);
        prep_w_kernel<<<(128 * 384 + 255) / 256, 256, 0, stream>>>(W_h2, Wp_h2, 128);
        prep_w_kernel<<<(64 * 384 + 255) / 256, 256, 0, stream>>>(W_out, Wp_out, 64);

        spmm_kernel<<<grid16, 256, 0, stream>>>(row_ptr, ecw, h, t1);
        fused_gemm_kernel<128, true, false, false><<<grid16, 256, 0, stream>>>(
            row_ptr, ecw, h, t1, Wp_in, b_in, h);
        spmm_kernel<<<grid16, 256, 0, stream>>>(row_ptr, ecw, h, t1);
        fused_gemm_kernel<128, true, true, false><<<grid16, 256, 0, stream>>>(
            row_ptr, ecw, h, t1, Wp_h1, b_h1, h);
        spmm_kernel<<<grid16, 256, 0, stream>>>(row_ptr, ecw, h, t1);
        fused_gemm_kernel<128, true, true, false><<<grid16, 256, 0, stream>>>(
            row_ptr, ecw, h, t1, Wp_h2, b_h2, h);
        spmm_kernel<<<grid16, 256, 0, stream>>>(row_ptr, ecw, h, t1);
        fused_gemm_kernel<64, false, false, true><<<grid16, 256, 0, stream>>>(
            row_ptr, ecw, h, t1, Wp_out, b_out, d_out);
    }
}

// Round 10
// 726.127 us; speedup vs baseline: 1.0849x; 1.0849x over previous
//
#include <hip/hip_runtime.h>
#include <hip/hip_bf16.h>
#include <stdint.h>
#include <stddef.h>

#define N_NODES 100000
#define N_EDGES 1600000
#define FEAT 128
#define NB_SCAN ((N_NODES + 255) / 256)   // 391 blocks of 256 for the scan
#define LDS_PITCH 136                     // u16; 272 B/row: uniform bank spread for b128
#define CAP 24                            // edges per gather chunk
#define NL (CAP / 4)                      // 6 load instructions per chunk
#define NBKT ((N_NODES + 255) / 256)      // 391 row-buckets of 256 rows
#define BCAP 8160                         // slots per bucket (mean 4096, +63 sigma)
#define EPB 2048                          // edges per phase-1 block (782 blocks, ~3/CU)

typedef __attribute__((ext_vector_type(8))) short bf16x8;
typedef __attribute__((ext_vector_type(4))) float f32x4;
typedef unsigned short u16;

__device__ __forceinline__ float bf2f(u16 u) {
    union { unsigned int i; float f; } v; v.i = ((unsigned int)u) << 16; return v.f;
}
__device__ __forceinline__ u16 f2bf(float f) {
    union { float f; unsigned int i; } v; v.f = f;
    unsigned int x = v.i;
    return (u16)((x + 0x7fffu + ((x >> 16) & 1u)) >> 16);   // round-nearest-even
}

// ---------------- CSR build: legacy kernels (fallback path) ----------------

__global__ void hist_kernel(const int* __restrict__ rows, int* __restrict__ counts) {
    int e = blockIdx.x * blockDim.x + threadIdx.x;
    if (e < N_EDGES) {
        int r = rows[e];
        r = min(max(r, 0), N_NODES - 1);
        atomicAdd(&counts[r], 1);
    }
}

__global__ void reduce_counts_kernel(const int* __restrict__ counts, int* __restrict__ bsum) {
    __shared__ int s[256];
    int i = blockIdx.x * 256 + threadIdx.x;
    int v = (i < N_NODES) ? counts[i] : 0;
    s[threadIdx.x] = v; __syncthreads();
    for (int off = 128; off > 0; off >>= 1) {
        if (threadIdx.x < off) s[threadIdx.x] += s[threadIdx.x + off];
        __syncthreads();
    }
    if (threadIdx.x == 0) bsum[blockIdx.x] = s[0];
}

__global__ void scan_bsums_kernel(int* __restrict__ bsum, int* __restrict__ row_ptr) {
    __shared__ int s[512];
    int t = threadIdx.x;
    int v = (t < NB_SCAN) ? bsum[t] : 0;
    s[t] = v; __syncthreads();
    for (int off = 1; off < 512; off <<= 1) {
        int x = (t >= off) ? s[t - off] : 0;
        __syncthreads();
        s[t] += x;
        __syncthreads();
    }
    if (t < NB_SCAN) bsum[t] = s[t] - v;              // exclusive
    if (t == NB_SCAN - 1) row_ptr[N_NODES] = s[t];    // total (= N_EDGES)
}

// also zeroes counts so it can be reused as the scatter fill array
__global__ void write_rowptr_kernel(int* __restrict__ counts, const int* __restrict__ bsum,
                                    int* __restrict__ row_ptr) {
    __shared__ int s[256];
    int i = blockIdx.x * 256 + threadIdx.x;
    int v = (i < N_NODES) ? counts[i] : 0;
    s[threadIdx.x] = v; __syncthreads();
    for (int off = 1; off < 256; off <<= 1) {
        int x = (threadIdx.x >= off) ? s[threadIdx.x - off] : 0;
        __syncthreads();
        s[threadIdx.x] += x;
        __syncthreads();
    }
    if (i < N_NODES) {
        row_ptr[i] = bsum[blockIdx.x] + s[threadIdx.x] - v;  // exclusive
        counts[i] = 0;                                       // becomes fill[]
    }
}

// legacy random scatter (fallback path only)
__global__ void scatter_kernel(const int* __restrict__ rows, const int* __restrict__ cols,
                               const float* __restrict__ w, const int* __restrict__ row_ptr,
                               int* __restrict__ fill, int2* __restrict__ ecw) {
    int e = blockIdx.x * blockDim.x + threadIdx.x;
    if (e < N_EDGES) {
        int r = rows[e];
        r = min(max(r, 0), N_NODES - 1);
        int pos = row_ptr[r] + atomicAdd(&fill[r], 1);
        pos = min(max(pos, 0), N_EDGES - 1);
        int c = cols[e];
        c = min(max(c, 0), N_NODES - 1);
        ecw[pos] = make_int2(c, __float_as_int(w[e]));
    }
}

// ---------------- CSR build v3: bucketed, write-merged, 3 kernels ----------
// Phase 1: blocks of EPB edges. LDS hist over NBKT buckets (256 rows each),
// one global reservation atomic per (block,bucket), then compacted writes.
// Payload packs (col | row_local<<20, w_bits) into int2.

__global__ __launch_bounds__(256) void bucket_p1_kernel(const int* __restrict__ rows,
                                                        const int* __restrict__ cols,
                                                        const float* __restrict__ w,
                                                        int* __restrict__ gcnt,
                                                        int2* __restrict__ bbuf) {
    __shared__ int s_cnt[NBKT];
    __shared__ int s_base[NBKT];
    int tid = threadIdx.x;
    for (int b = tid; b < NBKT; b += 256) s_cnt[b] = 0;
    __syncthreads();
    int e0 = blockIdx.x * EPB;
#pragma unroll
    for (int it = 0; it < EPB / 256; ++it) {
        int e = e0 + it * 256 + tid;
        if (e < N_EDGES) {
            int r = min(max(rows[e], 0), N_NODES - 1);
            atomicAdd(&s_cnt[r >> 8], 1);
        }
    }
    __syncthreads();
    for (int b = tid; b < NBKT; b += 256) {
        s_base[b] = atomicAdd(&gcnt[b], s_cnt[b]);
        s_cnt[b] = 0;
    }
    __syncthreads();
#pragma unroll
    for (int it = 0; it < EPB / 256; ++it) {
        int e = e0 + it * 256 + tid;
        if (e < N_EDGES) {
            int r = min(max(rows[e], 0), N_NODES - 1);
            int b = r >> 8;
            int k = atomicAdd(&s_cnt[b], 1);
            int pos = min(s_base[b] + k, BCAP - 1);          // statistically impossible clamp
            int c = min(max(cols[e], 0), N_NODES - 1);
            bbuf[(size_t)b * BCAP + pos] = make_int2(c | ((r & 255) << 20), __float_as_int(w[e]));
        }
    }
}

// Phase 2: exclusive scan of bucket totals -> bucket bases (bsum), plus total.
__global__ void scan_gcnt_kernel(const int* __restrict__ gcnt, int* __restrict__ bsum,
                                 int* __restrict__ row_ptr) {
    __shared__ int s[512];
    int t = threadIdx.x;
    int v = (t < NBKT) ? min(gcnt[t], BCAP) : 0;
    s[t] = v; __syncthreads();
    for (int off = 1; off < 512; off <<= 1) {
        int x = (t >= off) ? s[t - off] : 0;
        __syncthreads();
        s[t] += x;
        __syncthreads();
    }
    if (t < NBKT) bsum[t] = s[t] - v;                 // exclusive bucket base
    if (t == NBKT - 1) row_ptr[N_NODES] = s[t];       // total
}

// Phase 3: one block per bucket — LDS per-row histogram, LDS exclusive scan,
// write row_ptr for its 256 rows, then write-merged scatter into the bucket's
// contiguous block-exclusive ecw window. Fill counters entirely in LDS.
__global__ __launch_bounds__(256) void bucket_finalize_kernel(const int* __restrict__ gcnt,
                                                              const int* __restrict__ bsum,
                                                              const int2* __restrict__ bbuf,
                                                              int* __restrict__ row_ptr,
                                                              int2* __restrict__ ecw) {
    __shared__ int s_cnt[256];
    __shared__ int s_pos[256];
    int b = blockIdx.x, tid = threadIdx.x;
    int base = bsum[b];
    int cnt = min(gcnt[b], BCAP);
    s_cnt[tid] = 0; __syncthreads();
    for (int i = tid; i < cnt; i += 256)
        atomicAdd(&s_cnt[bbuf[(size_t)b * BCAP + i].x >> 20], 1);
    __syncthreads();
    int v = s_cnt[tid];
    s_pos[tid] = v; __syncthreads();
    for (int off = 1; off < 256; off <<= 1) {
        int x = (tid >= off) ? s_pos[tid - off] : 0;
        __syncthreads();
        s_pos[tid] += x;
        __syncthreads();
    }
    int excl = s_pos[tid] - v;
    int r = b * 256 + tid;
    if (r < N_NODES) row_ptr[r] = base + excl;
    s_cnt[tid] = excl;                                 // reuse as running fill
    __syncthreads();
    for (int i = tid; i < cnt; i += 256) {
        int2 p = bbuf[(size_t)b * BCAP + i];
        int rl = p.x >> 20;
        int pos = base + atomicAdd(&s_cnt[rl], 1);
        pos = min(max(pos, 0), N_EDGES - 1);
        ecw[pos] = make_int2(p.x & 0xFFFFF, p.y);
    }
}

// -------- weight prep ------------------------------------------------------
__device__ __forceinline__ float w_fold(const float* W, int o, int k) {
    if (k < 128)      return W[o * 384 + k] - W[o * 384 + 256 + k];
    else if (k < 256) return W[o * 384 + k];
    else              return 2.0f * W[o * 384 + k];
}

__global__ void prep_w_kernel(const float* __restrict__ W, u16* __restrict__ Wp, int O) {
    int i = blockIdx.x * blockDim.x + threadIdx.x;
    if (i >= O * 384) return;
    int o = i / 384, k = i % 384;
    Wp[i] = f2bf(w_fold(W, o, k));
}

// MFMA-fragment-packed W', all 4 weights in one launch.
// unit = (ot*12+kk)*64+lane; lane=q*16+r holds col ot*16+r, k kk*32+q*8..+8.
__global__ void prep_w2_all_kernel(const float* __restrict__ Wa, const float* __restrict__ Wb,
                                   const float* __restrict__ Wc, const float* __restrict__ Wd,
                                   u16* __restrict__ Pa, u16* __restrict__ Pb,
                                   u16* __restrict__ Pc, u16* __restrict__ Pd) {
    int i = blockIdx.x * blockDim.x + threadIdx.x;   // 3*6144 + 3072 = 21504 units
    const float* W; u16* P; int il;
    if (i < 6144)       { W = Wa; P = Pa; il = i; }
    else if (i < 12288) { W = Wb; P = Pb; il = i - 6144; }
    else if (i < 18432) { W = Wc; P = Pc; il = i - 12288; }
    else if (i < 21504) { W = Wd; P = Pd; il = i - 18432; }
    else return;
    int ot = il / 768;
    int rem = il % 768;
    int kk = rem / 64;
    int l = rem % 64;
    int q = l >> 4, r = l & 15;
    int o = ot * 16 + r;
    int kbase = kk * 32 + q * 8;
#pragma unroll
    for (int j = 0; j < 8; ++j)
        P[(size_t)il * 8 + j] = f2bf(w_fold(W, o, kbase + j));
}

// -------- x (f32) -> bf16, 4 elems per thread ----------

__global__ void cvt_kernel(const float* __restrict__ x, u16* __restrict__ y) {
    int i = blockIdx.x * blockDim.x + threadIdx.x;
    if (i >= N_NODES * FEAT / 4) return;
    float4 v = ((const float4*)x)[i];
    ushort4 o;
    o.x = f2bf(v.x); o.y = f2bf(v.y); o.z = f2bf(v.z); o.w = f2bf(v.w);
    ((ushort4*)y)[i] = o;
}

// -------- branch-free register gather primitives --------------------------

__device__ __forceinline__ void load_meta(const int2* __restrict__ ecw, int s, int n,
                                          int lane, int& call, float& wall) {
    int idx = s + max(0, min(lane, n - 1));       // clamp: branch-free
    idx = min(idx, N_EDGES - 1);                  // deg-0 last-row guard
    int2 cw = ecw[idx];
    call = cw.x;
    wall = (lane < n) ? __int_as_float(cw.y) : 0.f;   // cndmask, no branch
}

__device__ __forceinline__ void issue_row(const u16* __restrict__ X, int call,
                                          int g, int f, bf16x8* q) {
#pragma unroll
    for (int k = 0; k < NL; ++k) {
        int col = __shfl(call, k * 4 + g);
        q[k] = *(const bf16x8*)(X + (size_t)col * FEAT + f * 8);
    }
}

__device__ __forceinline__ void reduce_row(const bf16x8* q, float wall,
                                           int g, float* acc) {
#pragma unroll
    for (int k = 0; k < NL; ++k) {
        float wj = __shfl(wall, k * 4 + g);
#pragma unroll
        for (int j = 0; j < 8; ++j) acc[j] += wj * bf2f((u16)q[k][j]);
    }
}

// -------- SpMM v3 (proven best, round 8): ONE ROW PER WAVE ----------------
// At the confirmed per-CU miss-tracking cap (~3.75 TB/s), this is the
// highest-BW configuration measured (56.3 us/pass).

__global__ __launch_bounds__(256) void spmm1_kernel(const int* __restrict__ row_ptr,
                                                    const int2* __restrict__ ecw,
                                                    const u16* __restrict__ X,
                                                    u16* __restrict__ Y) {
    int lane = threadIdx.x & 63;
    int g = lane >> 4, f = lane & 15;
    int rr = (blockIdx.x * blockDim.x + threadIdx.x) >> 6;   // 1 row per wave

    int s = row_ptr[rr], e = row_ptr[rr + 1];
    float acc[8];
#pragma unroll
    for (int j = 0; j < 8; ++j) acc[j] = 0.f;

    {   // main chunk (covers 98% of Poisson-16 rows entirely)
        int call; float wall;
        load_meta(ecw, s, min(e - s, CAP), lane, call, wall);
        bf16x8 q[NL];
        issue_row(X, call, g, f, q);
        reduce_row(q, wall, g, acc);
    }
    for (int cs = s + CAP; cs < e; cs += CAP) {   // rare tail (deg > 24)
        int c2; float w2;
        load_meta(ecw, cs, min(e - cs, CAP), lane, c2, w2);
        bf16x8 qt[NL];
        issue_row(X, c2, g, f, qt);
        reduce_row(qt, w2, g, acc);
    }

#pragma unroll
    for (int j = 0; j < 8; ++j) {
        acc[j] += __shfl_xor(acc[j], 16);
        acc[j] += __shfl_xor(acc[j], 32);
    }
    if (g == 0) {
        u16 tmp[8];
#pragma unroll
        for (int j = 0; j < 8; ++j) tmp[j] = f2bf(acc[j]);
        *(bf16x8*)(Y + (size_t)rr * FEAT + f * 8) = *(const bf16x8*)tmp;
    }
}

// -------- gather4 (fallback fused path only) ------------------------------

__device__ __forceinline__ void gather4(const int* __restrict__ row_ptr,
                                        const int2* __restrict__ ecw,
                                        const u16* __restrict__ X,
                                        int r0, int lane, int g, int f,
                                        float acc[4][8]) {
    int s[4], e[4];
    int call[4]; float wall[4];
#pragma unroll
    for (int y = 0; y < 4; ++y) {
        s[y] = row_ptr[r0 + y];
        e[y] = row_ptr[r0 + y + 1];
    }
#pragma unroll
    for (int y = 0; y < 4; ++y)
        load_meta(ecw, s[y], min(e[y] - s[y], CAP), lane, call[y], wall[y]);
#pragma unroll
    for (int y = 0; y < 4; ++y)
#pragma unroll
        for (int j = 0; j < 8; ++j) acc[y][j] = 0.f;

    bf16x8 q0[NL], q1[NL], q2[NL], q3[NL];
    issue_row(X, call[0], g, f, q0);
    issue_row(X, call[1], g, f, q1);
    reduce_row(q0, wall[0], g, acc[0]);
    issue_row(X, call[2], g, f, q2);
    reduce_row(q1, wall[1], g, acc[1]);
    issue_row(X, call[3], g, f, q3);
    reduce_row(q2, wall[2], g, acc[2]);
    reduce_row(q3, wall[3], g, acc[3]);

#pragma unroll
    for (int y = 0; y < 4; ++y) {
        for (int cs = s[y] + CAP; cs < e[y]; cs += CAP) {
            int c2; float w2;
            load_meta(ecw, cs, min(e[y] - cs, CAP), lane, c2, w2);
            bf16x8 qt[NL];
            issue_row(X, c2, g, f, qt);
            reduce_row(qt, w2, g, acc[y]);
        }
    }

#pragma unroll
    for (int y = 0; y < 4; ++y)
#pragma unroll
        for (int j = 0; j < 8; ++j) {
            acc[y][j] += __shfl_xor(acc[y][j], 16);
            acc[y][j] += __shfl_xor(acc[y][j], 32);
        }
}

// legacy 4-rows-per-wave spmm (fallback path)
__global__ __launch_bounds__(256) void spmm_kernel(const int* __restrict__ row_ptr,
                                                   const int2* __restrict__ ecw,
                                                   const u16* __restrict__ X,
                                                   u16* __restrict__ Y) {
    int wid = threadIdx.x >> 6;
    int lane = threadIdx.x & 63;
    int g = lane >> 4, f = lane & 15;
    int r0 = blockIdx.x * 16 + wid * 4;

    float acc[4][8];
    gather4(row_ptr, ecw, X, r0, lane, g, f, acc);

    if (g == 0) {
#pragma unroll
        for (int y = 0; y < 4; ++y) {
            u16 tmp[8];
#pragma unroll
            for (int j = 0; j < 8; ++j) tmp[j] = f2bf(acc[y][j]);
            *(bf16x8*)(Y + (size_t)(r0 + y) * FEAT + f * 8) = *(const bf16x8*)tmp;
        }
    }
}

// ------- streaming GEMM v2 (proven best, round 8): LDS-staged 32-row A tile,
//         fragment-packed Wp2.

template <int O, bool RELU, bool RES, bool OUT_F32>
__global__ __launch_bounds__(256) void gemm_kernel(const u16* __restrict__ H,
                                                   const u16* __restrict__ T1,
                                                   const u16* __restrict__ S2,
                                                   const u16* __restrict__ Wp2,
                                                   const float* __restrict__ bias,
                                                   void* __restrict__ outv) {
    __shared__ __align__(16) u16 sA[3][32][LDS_PITCH];    // 25.5 KB
    int tid = threadIdx.x;
    int m0 = blockIdx.x * 32;                             // N_NODES % 32 == 0

#pragma unroll
    for (int p = 0; p < 3; ++p) {
        const u16* sp = (p == 0) ? H : (p == 1) ? T1 : S2;
#pragma unroll
        for (int u = 0; u < 2; ++u) {
            int unit = u * 256 + tid;
            int row = unit >> 4, seg = unit & 15;
            *(bf16x8*)&sA[p][row][seg * 8] =
                *(const bf16x8*)(sp + (size_t)(m0 + row) * FEAT + seg * 8);
        }
    }
    __syncthreads();

    int lane = tid & 63, wid = tid >> 6;
    int r = lane & 15, q = lane >> 4;
    constexpr int NW = O / 64;          // 2 for O=128, 1 for O=64
    f32x4 acc0[NW], acc1[NW];
#pragma unroll
    for (int t = 0; t < NW; ++t) {
        acc0[t] = (f32x4){0.f, 0.f, 0.f, 0.f};
        acc1[t] = (f32x4){0.f, 0.f, 0.f, 0.f};
    }

#pragma unroll
    for (int kk = 0; kk < 12; ++kk) {
        int p = kk >> 2, ko = kk & 3;
        bf16x8 af0 = *(const bf16x8*)&sA[p][r][ko * 32 + q * 8];
        bf16x8 af1 = *(const bf16x8*)&sA[p][16 + r][ko * 32 + q * 8];
#pragma unroll
        for (int t = 0; t < NW; ++t) {
            int ot = wid * NW + t;
            bf16x8 bfr = *(const bf16x8*)(Wp2 + ((size_t)(ot * 12 + kk) * 64 + lane) * 8);
            acc0[t] = __builtin_amdgcn_mfma_f32_16x16x32_bf16(af0, bfr, acc0[t], 0, 0, 0);
            acc1[t] = __builtin_amdgcn_mfma_f32_16x16x32_bf16(af1, bfr, acc1[t], 0, 0, 0);
        }
    }

#pragma unroll
    for (int t = 0; t < NW; ++t) {
        int col = (wid * NW + t) * 16 + r;
        float bv = bias[col];
#pragma unroll
        for (int i = 0; i < 4; ++i) {
            int lrow = q * 4 + i;
            float v0 = acc0[t][i] + bv;
            if (RES)  v0 += bf2f(sA[0][lrow][col]);
            if (RELU) v0 = fmaxf(v0, 0.f);
            float v1 = acc1[t][i] + bv;
            if (RES)  v1 += bf2f(sA[0][16 + lrow][col]);
            if (RELU) v1 = fmaxf(v1, 0.f);
            if (OUT_F32) {
                ((float*)outv)[(size_t)(m0 + lrow) * O + col] = v0;
                ((float*)outv)[(size_t)(m0 + 16 + lrow) * O + col] = v1;
            } else {
                ((u16*)outv)[(size_t)(m0 + lrow) * O + col] = f2bf(v0);
                ((u16*)outv)[(size_t)(m0 + 16 + lrow) * O + col] = f2bf(v1);
            }
        }
    }
}

// ------- fallback fused kernel (ws too small for s2): proven r2 path --------

template <int O, bool RELU, bool RES, bool OUT_F32>
__global__ __launch_bounds__(256) void fused_gemm_kernel(const int* __restrict__ row_ptr,
                                                         const int2* __restrict__ ecw,
                                                         const u16* __restrict__ H,
                                                         const u16* __restrict__ T1,
                                                         const u16* __restrict__ Wp,
                                                         const float* __restrict__ bias,
                                                         void* __restrict__ outv) {
    __shared__ __align__(16) u16 sT[16 * LDS_PITCH];
    int wid = threadIdx.x >> 6;
    int lane = threadIdx.x & 63;
    int g = lane >> 4, f = lane & 15;
    int m0 = blockIdx.x * 16;

    {
        float acc[4][8];
        gather4(row_ptr, ecw, T1, m0 + wid * 4, lane, g, f, acc);
        if (g == 0) {
#pragma unroll
            for (int y = 0; y < 4; ++y) {
                u16 tmp[8];
#pragma unroll
                for (int j = 0; j < 8; ++j) tmp[j] = f2bf(acc[y][j]);
                *(bf16x8*)(sT + (wid * 4 + y) * LDS_PITCH + f * 8) = *(const bf16x8*)tmp;
            }
        }
    }
    __syncthreads();

    int r = f, q = g;
    constexpr int NT = O / 16;
    constexpr int NW = NT / 4;
    f32x4 acc[NW];
#pragma unroll
    for (int t = 0; t < NW; ++t) acc[t] = (f32x4){0.f, 0.f, 0.f, 0.f};

#pragma unroll
    for (int kk = 0; kk < 12; ++kk) {
        bf16x8 af;
        if (kk < 4)
            af = *(const bf16x8*)(H + (size_t)(m0 + r) * FEAT + kk * 32 + q * 8);
        else if (kk < 8)
            af = *(const bf16x8*)(T1 + (size_t)(m0 + r) * FEAT + (kk - 4) * 32 + q * 8);
        else
            af = *(const bf16x8*)(sT + r * LDS_PITCH + (kk - 8) * 32 + q * 8);
#pragma unroll
        for (int t = 0; t < NW; ++t) {
            int ot = wid * NW + t;
            bf16x8 bfr = *(const bf16x8*)(Wp + (size_t)(ot * 16 + r) * 384 + kk * 32 + q * 8);
            acc[t] = __builtin_amdgcn_mfma_f32_16x16x32_bf16(af, bfr, acc[t], 0, 0, 0);
        }
    }

#pragma unroll
    for (int t = 0; t < NW; ++t) {
        int col = (wid * NW + t) * 16 + r;
        float bv = bias[col];
#pragma unroll
        for (int i = 0; i < 4; ++i) {
            int row = m0 + q * 4 + i;
            float v = acc[t][i] + bv;
            if (RES)  v += bf2f(H[(size_t)row * FEAT + col]);
            if (RELU) v = fmaxf(v, 0.f);
            if (OUT_F32) ((float*)outv)[(size_t)row * O + col] = v;
            else         ((u16*)outv)[(size_t)row * O + col] = f2bf(v);
        }
    }
}

// ---------------- launcher ----------------

static inline size_t align_up(size_t x) { return (x + 255) & ~(size_t)255; }

extern "C" void kernel_launch(void* const* d_in, const int* in_sizes, int n_in,
                              void* d_out, int out_size, void* d_ws, size_t ws_size,
                              hipStream_t stream) {
    const float* x     = (const float*)d_in[0];
    const int*   ei    = (const int*)d_in[1];
    const float* ew    = (const float*)d_in[2];
    const float* W_in  = (const float*)d_in[3];
    const float* b_in  = (const float*)d_in[4];
    const float* W_h1  = (const float*)d_in[5];
    const float* b_h1  = (const float*)d_in[6];
    const float* W_h2  = (const float*)d_in[7];
    const float* b_h2  = (const float*)d_in[8];
    const float* W_out = (const float*)d_in[9];
    const float* b_out = (const float*)d_in[10];

    const int* rows = ei;
    const int* cols = ei + N_EDGES;

    // workspace layout
    char* w = (char*)d_ws;
    size_t off = 0;
    int* counts = (int*)(w + off);            off = align_up(off + (size_t)N_NODES * 4);   // fallback fill
    int* row_ptr= (int*)(w + off);            off = align_up(off + (size_t)(N_NODES + 1) * 4);
    int* bsum   = (int*)(w + off);            off = align_up(off + 512 * 4);
    int2* ecw   = (int2*)(w + off);           off = align_up(off + (size_t)N_EDGES * 8);
    u16* t1     = (u16*)(w + off);            off = align_up(off + (size_t)N_NODES * FEAT * 2);
    u16* h      = (u16*)(w + off);            off = align_up(off + (size_t)N_NODES * FEAT * 2);
    u16* Wp_in  = (u16*)(w + off);            off = align_up(off + (size_t)128 * 384 * 2);
    u16* Wp_h1  = (u16*)(w + off);            off = align_up(off + (size_t)128 * 384 * 2);
    u16* Wp_h2  = (u16*)(w + off);            off = align_up(off + (size_t)128 * 384 * 2);
    u16* Wp_out = (u16*)(w + off);            off = align_up(off + (size_t)64 * 384 * 2);
    // split path: s2 buffer (+25.6 MB, doubles as the CSR bucket buffer),
    // fragment-packed weights, bucket counters
    u16* s2     = (u16*)(w + off);            size_t off2 = align_up(off + (size_t)N_NODES * FEAT * 2);
    u16* W2_in  = (u16*)(w + off2);           off2 = align_up(off2 + (size_t)128 * 384 * 2);
    u16* W2_h1  = (u16*)(w + off2);           off2 = align_up(off2 + (size_t)128 * 384 * 2);
    u16* W2_h2  = (u16*)(w + off2);           off2 = align_up(off2 + (size_t)128 * 384 * 2);
    u16* W2_out = (u16*)(w + off2);           off2 = align_up(off2 + (size_t)64 * 384 * 2);
    int* gcnt   = (int*)(w + off2);           off2 = align_up(off2 + (size_t)NBKT * 4);
    const bool use_split = (ws_size >= off2);
    static_assert((size_t)NBKT * BCAP * 8 <= (size_t)N_NODES * FEAT * 2, "bucket buffer exceeds s2");

    cvt_kernel<<<(N_NODES * FEAT / 4 + 255) / 256, 256, 0, stream>>>(x, h);

    const int grid16 = N_NODES / 16;         // 6250 blocks (fallback)
    const int grid32 = N_NODES / 32;         // 3125 blocks: 32-row gemm tiles
    const int grid1  = N_NODES * 64 / 256;   // 25000 blocks: 1 row per wave

    if (use_split) {
        // CSR build v3: 3 kernels, write-merged, all fill counters in LDS
        hipMemsetAsync(gcnt, 0, (size_t)NBKT * 4, stream);
        int2* bbuf = (int2*)s2;
        bucket_p1_kernel<<<(N_EDGES + EPB - 1) / EPB, 256, 0, stream>>>(rows, cols, ew, gcnt, bbuf);
        scan_gcnt_kernel<<<1, 512, 0, stream>>>(gcnt, bsum, row_ptr);
        bucket_finalize_kernel<<<NBKT, 256, 0, stream>>>(gcnt, bsum, bbuf, row_ptr, ecw);

        prep_w2_all_kernel<<<(21504 + 255) / 256, 256, 0, stream>>>(
            W_in, W_h1, W_h2, W_out, W2_in, W2_h1, W2_h2, W2_out);

        // Layer 1
        spmm1_kernel<<<grid1, 256, 0, stream>>>(row_ptr, ecw, h, t1);
        spmm1_kernel<<<grid1, 256, 0, stream>>>(row_ptr, ecw, t1, s2);
        gemm_kernel<128, true, false, false><<<grid32, 256, 0, stream>>>(h, t1, s2, W2_in, b_in, h);
        // Layer 2
        spmm1_kernel<<<grid1, 256, 0, stream>>>(row_ptr, ecw, h, t1);
        spmm1_kernel<<<grid1, 256, 0, stream>>>(row_ptr, ecw, t1, s2);
        gemm_kernel<128, true, true, false><<<grid32, 256, 0, stream>>>(h, t1, s2, W2_h1, b_h1, h);
        // Layer 3
        spmm1_kernel<<<grid1, 256, 0, stream>>>(row_ptr, ecw, h, t1);
        spmm1_kernel<<<grid1, 256, 0, stream>>>(row_ptr, ecw, t1, s2);
        gemm_kernel<128, true, true, false><<<grid32, 256, 0, stream>>>(h, t1, s2, W2_h2, b_h2, h);
        // Layer 4 (O=64, f32 out)
        spmm1_kernel<<<grid1, 256, 0, stream>>>(row_ptr, ecw, h, t1);
        spmm1_kernel<<<grid1, 256, 0, stream>>>(row_ptr, ecw, t1, s2);
        gemm_kernel<64, false, false, true><<<grid32, 256, 0, stream>>>(h, t1, s2, W2_out, b_out, d_out);
    } else {
        // fallback: legacy CSR build + fused path
        hipMemsetAsync(counts, 0, (size_t)N_NODES * 4, stream);
        hist_kernel<<<N_EDGES / 256, 256, 0, stream>>>(rows, counts);
        reduce_counts_kernel<<<NB_SCAN, 256, 0, stream>>>(counts, bsum);
        scan_bsums_kernel<<<1, 512, 0, stream>>>(bsum, row_ptr);
        write_rowptr_kernel<<<NB_SCAN, 256, 0, stream>>>(counts, bsum, row_ptr);
        scatter_kernel<<<N_EDGES / 256, 256, 0, stream>>>(rows, cols, ew, row_ptr, counts, ecw);

        prep_w_kernel<<<(128 * 384 + 255) / 256, 256, 0, stream>>>(W_in, Wp_in, 128);
        prep_w_kernel<<<(128 * 384 + 255) / 256, 256, 0, stream>>>(W_h1, Wp_h1, 128);
        prep_w_kernel<<<(128 * 384 + 255) / 256, 256, 0, stream>>>(W_h2, Wp_h2, 128);
        prep_w_kernel<<<(64 * 384 + 255) / 256, 256, 0, stream>>>(W_out, Wp_out, 64);

        spmm_kernel<<<grid16, 256, 0, stream>>>(row_ptr, ecw, h, t1);
        fused_gemm_kernel<128, true, false, false><<<grid16, 256, 0, stream>>>(
            row_ptr, ecw, h, t1, Wp_in, b_in, h);
        spmm_kernel<<<grid16, 256, 0, stream>>>(row_ptr, ecw, h, t1);
        fused_gemm_kernel<128, true, true, false><<<grid16, 256, 0, stream>>>(
            row_ptr, ecw, h, t1, Wp_h1, b_h1, h);
        spmm_kernel<<<grid16, 256, 0, stream>>>(row_ptr, ecw, h, t1);
        fused_gemm_kernel<128, true, true, false><<<grid16, 256, 0, stream>>>(
            row_ptr, ecw, h, t1, Wp_h2, b_h2, h);
        spmm_kernel<<<grid16, 256, 0, stream>>>(row_ptr, ecw, h, t1);
        fused_gemm_kernel<64, false, false, true><<<grid16, 256, 0, stream>>>(
            row_ptr, ecw, h, t1, Wp_out, b_out, d_out);
    }
}

// Round 11
// 700.807 us; speedup vs baseline: 1.1241x; 1.0361x over previous
//
#include <hip/hip_runtime.h>
#include <hip/hip_bf16.h>
#include <stdint.h>
#include <stddef.h>

#define N_NODES 100000
#define N_EDGES 1600000
#define FEAT 128
#define NB_SCAN ((N_NODES + 255) / 256)   // 391 blocks of 256 for the scan
#define LDS_PITCH 136                     // u16; 272 B/row: uniform bank spread for b128
#define CAP 24                            // edges per gather chunk
#define NL (CAP / 4)                      // 6 load instructions per chunk
#define NBKT ((N_NODES + 255) / 256)      // 391 row-buckets of 256 rows
#define EPB 2048                          // edges per CSR block
#define NBLK ((N_EDGES + EPB - 1) / EPB)  // 782 CSR blocks
#define EPT (EPB / 256)                   // 8 edges per thread

typedef __attribute__((ext_vector_type(8))) short bf16x8;
typedef __attribute__((ext_vector_type(4))) float f32x4;
typedef unsigned short u16;

__device__ __forceinline__ float bf2f(u16 u) {
    union { unsigned int i; float f; } v; v.i = ((unsigned int)u) << 16; return v.f;
}
__device__ __forceinline__ u16 f2bf(float f) {
    union { float f; unsigned int i; } v; v.f = f;
    unsigned int x = v.i;
    return (u16)((x + 0x7fffu + ((x >> 16) & 1u)) >> 16);   // round-nearest-even
}

// ---------------- CSR build: legacy kernels (fallback path) ----------------

__global__ void hist_kernel(const int* __restrict__ rows, int* __restrict__ counts) {
    int e = blockIdx.x * blockDim.x + threadIdx.x;
    if (e < N_EDGES) {
        int r = rows[e];
        r = min(max(r, 0), N_NODES - 1);
        atomicAdd(&counts[r], 1);
    }
}

__global__ void reduce_counts_kernel(const int* __restrict__ counts, int* __restrict__ bsum) {
    __shared__ int s[256];
    int i = blockIdx.x * 256 + threadIdx.x;
    int v = (i < N_NODES) ? counts[i] : 0;
    s[threadIdx.x] = v; __syncthreads();
    for (int off = 128; off > 0; off >>= 1) {
        if (threadIdx.x < off) s[threadIdx.x] += s[threadIdx.x + off];
        __syncthreads();
    }
    if (threadIdx.x == 0) bsum[blockIdx.x] = s[0];
}

__global__ void scan_bsums_kernel(int* __restrict__ bsum, int* __restrict__ row_ptr) {
    __shared__ int s[512];
    int t = threadIdx.x;
    int v = (t < NB_SCAN) ? bsum[t] : 0;
    s[t] = v; __syncthreads();
    for (int off = 1; off < 512; off <<= 1) {
        int x = (t >= off) ? s[t - off] : 0;
        __syncthreads();
        s[t] += x;
        __syncthreads();
    }
    if (t < NB_SCAN) bsum[t] = s[t] - v;              // exclusive
    if (t == NB_SCAN - 1) row_ptr[N_NODES] = s[t];    // total (= N_EDGES)
}

// also zeroes counts so it can be reused as the scatter fill array
__global__ void write_rowptr_kernel(int* __restrict__ counts, const int* __restrict__ bsum,
                                    int* __restrict__ row_ptr) {
    __shared__ int s[256];
    int i = blockIdx.x * 256 + threadIdx.x;
    int v = (i < N_NODES) ? counts[i] : 0;
    s[threadIdx.x] = v; __syncthreads();
    for (int off = 1; off < 256; off <<= 1) {
        int x = (threadIdx.x >= off) ? s[threadIdx.x - off] : 0;
        __syncthreads();
        s[threadIdx.x] += x;
        __syncthreads();
    }
    if (i < N_NODES) {
        row_ptr[i] = bsum[blockIdx.x] + s[threadIdx.x] - v;  // exclusive
        counts[i] = 0;                                       // becomes fill[]
    }
}

// legacy random scatter (fallback path only)
__global__ void scatter_kernel(const int* __restrict__ rows, const int* __restrict__ cols,
                               const float* __restrict__ w, const int* __restrict__ row_ptr,
                               int* __restrict__ fill, int2* __restrict__ ecw) {
    int e = blockIdx.x * blockDim.x + threadIdx.x;
    if (e < N_EDGES) {
        int r = rows[e];
        r = min(max(r, 0), N_NODES - 1);
        int pos = row_ptr[r] + atomicAdd(&fill[r], 1);
        pos = min(max(pos, 0), N_EDGES - 1);
        int c = cols[e];
        c = min(max(c, 0), N_NODES - 1);
        ecw[pos] = make_int2(c, __float_as_int(w[e]));
    }
}

// ---------------- CSR build v4: deterministic, zero global atomics ---------
// passA: per-block LDS hist over NBKT buckets -> coalesced pcnt[blk][b] write.
// scanP: per-bucket exclusive scan over blocks -> block bases, bucket totals.
// scanG: exclusive scan of bucket totals -> packed bucket bases bsum[0..NBKT].
// passB: re-read edges, LDS counting-sort by bucket, write payload to exact
//        precomputed slots in ebuf (sorted order -> write-merged runs).
// finalize: per-bucket row hist + scan -> row_ptr; permute ebuf -> ecw.

__global__ __launch_bounds__(256) void csr_passA_kernel(const int* __restrict__ rows,
                                                        int* __restrict__ pcnt) {
    __shared__ int s_cnt[NBKT];
    int tid = threadIdx.x, blk = blockIdx.x;
    for (int b = tid; b < NBKT; b += 256) s_cnt[b] = 0;
    __syncthreads();
    int e0 = blk * EPB;
#pragma unroll
    for (int it = 0; it < EPT; ++it) {
        int e = e0 + it * 256 + tid;
        if (e < N_EDGES) {
            int r = min(max(rows[e], 0), N_NODES - 1);
            atomicAdd(&s_cnt[r >> 8], 1);
        }
    }
    __syncthreads();
    for (int b = tid; b < NBKT; b += 256)
        pcnt[(size_t)blk * NBKT + b] = s_cnt[b];      // coalesced 1.5 KB store
}

__global__ __launch_bounds__(256) void csr_scanP_kernel(int* __restrict__ pcnt,
                                                        int* __restrict__ gtot) {
    __shared__ int s[256];
    int b = blockIdx.x, tid = threadIdx.x;
    int carry = 0;
    for (int c = 0; c < (NBLK + 255) / 256; ++c) {
        int idx = c * 256 + tid;
        int v = (idx < NBLK) ? pcnt[(size_t)idx * NBKT + b] : 0;
        s[tid] = v; __syncthreads();
        for (int off = 1; off < 256; off <<= 1) {
            int x = (tid >= off) ? s[tid - off] : 0;
            __syncthreads();
            s[tid] += x;
            __syncthreads();
        }
        if (idx < NBLK) pcnt[(size_t)idx * NBKT + b] = carry + s[tid] - v;  // exclusive
        carry += s[255];
        __syncthreads();
    }
    if (tid == 0) gtot[b] = carry;
}

__global__ void csr_scanG_kernel(const int* __restrict__ gtot, int* __restrict__ bsum,
                                 int* __restrict__ row_ptr) {
    __shared__ int s[512];
    int t = threadIdx.x;
    int v = (t < NBKT) ? gtot[t] : 0;
    s[t] = v; __syncthreads();
    for (int off = 1; off < 512; off <<= 1) {
        int x = (t >= off) ? s[t - off] : 0;
        __syncthreads();
        s[t] += x;
        __syncthreads();
    }
    if (t < NBKT) bsum[t] = s[t] - v;                 // exclusive bucket base
    if (t == NBKT - 1) {
        bsum[NBKT] = s[t];                            // total
        row_ptr[N_NODES] = s[t];
    }
}

__global__ __launch_bounds__(256) void csr_passB_kernel(const int* __restrict__ rows,
                                                        const int* __restrict__ cols,
                                                        const float* __restrict__ w,
                                                        const int* __restrict__ pcnt,
                                                        const int* __restrict__ bsum,
                                                        int2* __restrict__ ebuf) {
    __shared__ int s_base[NBKT];      // global dest base per bucket for this block
    __shared__ int s_cnt[NBKT];       // hist, then fill
    __shared__ int s_off[NBKT];       // exclusive offsets in sorted LDS array
    __shared__ int s_scan[512];
    __shared__ int2 s_sorted[EPB];    // 16 KB payload sorted by bucket
    __shared__ int s_dst[EPB];        // 8 KB destination slots
    int tid = threadIdx.x, blk = blockIdx.x;
    for (int b = tid; b < NBKT; b += 256) {
        s_base[b] = bsum[b] + pcnt[(size_t)blk * NBKT + b];
        s_cnt[b] = 0;
    }
    __syncthreads();
    int e0 = blk * EPB;
    int n = min(N_EDGES - e0, EPB);

    int2 pay[EPT]; int pb[EPT];
#pragma unroll
    for (int it = 0; it < EPT; ++it) {
        int e = e0 + it * 256 + tid;
        if (e < N_EDGES) {
            int r = min(max(rows[e], 0), N_NODES - 1);
            int c = min(max(cols[e], 0), N_NODES - 1);
            pay[it] = make_int2(c | ((r & 255) << 20), __float_as_int(w[e]));
            pb[it] = r >> 8;
            atomicAdd(&s_cnt[pb[it]], 1);
        } else {
            pb[it] = -1;
        }
    }
    __syncthreads();
    // exclusive scan of s_cnt[0..NBKT) via 512-wide Hillis-Steele, 2 elems/thread
    s_scan[tid] = (tid < NBKT) ? s_cnt[tid] : 0;
    s_scan[tid + 256] = (tid + 256 < NBKT) ? s_cnt[tid + 256] : 0;
    __syncthreads();
    for (int off = 1; off < 512; off <<= 1) {
        int a = (tid >= off) ? s_scan[tid - off] : 0;
        int b2 = (tid + 256 >= off) ? s_scan[tid + 256 - off] : 0;
        __syncthreads();
        s_scan[tid] += a;
        s_scan[tid + 256] += b2;
        __syncthreads();
    }
    for (int b = tid; b < NBKT; b += 256) {
        s_off[b] = s_scan[b] - s_cnt[b];
        s_cnt[b] = 0;                                  // becomes fill counter
    }
    __syncthreads();
    // place payload + dst into LDS, sorted by bucket
#pragma unroll
    for (int it = 0; it < EPT; ++it) {
        if (pb[it] >= 0) {
            int k = atomicAdd(&s_cnt[pb[it]], 1);
            int slot = s_off[pb[it]] + k;
            s_sorted[slot] = pay[it];
            s_dst[slot] = s_base[pb[it]] + k;
        }
    }
    __syncthreads();
    // linear write: consecutive lanes -> mostly-consecutive destinations
    for (int p = tid; p < n; p += 256)
        ebuf[s_dst[p]] = s_sorted[p];
}

__global__ __launch_bounds__(256) void csr_finalize_kernel(const int* __restrict__ bsum,
                                                           const int2* __restrict__ ebuf,
                                                           int* __restrict__ row_ptr,
                                                           int2* __restrict__ ecw) {
    __shared__ int s_cnt[256];
    __shared__ int s_pos[256];
    int b = blockIdx.x, tid = threadIdx.x;
    int base = bsum[b];
    int cnt = bsum[b + 1] - base;
    s_cnt[tid] = 0; __syncthreads();
    for (int i = tid; i < cnt; i += 256)
        atomicAdd(&s_cnt[ebuf[base + i].x >> 20], 1);
    __syncthreads();
    int v = s_cnt[tid];
    s_pos[tid] = v; __syncthreads();
    for (int off = 1; off < 256; off <<= 1) {
        int x = (tid >= off) ? s_pos[tid - off] : 0;
        __syncthreads();
        s_pos[tid] += x;
        __syncthreads();
    }
    int excl = s_pos[tid] - v;
    int r = b * 256 + tid;
    if (r < N_NODES) row_ptr[r] = base + excl;
    s_cnt[tid] = excl;                                 // running fill
    __syncthreads();
    for (int i = tid; i < cnt; i += 256) {
        int2 p = ebuf[base + i];
        int rl = p.x >> 20;
        int pos = base + atomicAdd(&s_cnt[rl], 1);
        pos = min(max(pos, 0), N_EDGES - 1);
        ecw[pos] = make_int2(p.x & 0xFFFFF, p.y);
    }
}

// -------- weight prep ------------------------------------------------------
__device__ __forceinline__ float w_fold(const float* W, int o, int k) {
    if (k < 128)      return W[o * 384 + k] - W[o * 384 + 256 + k];
    else if (k < 256) return W[o * 384 + k];
    else              return 2.0f * W[o * 384 + k];
}

__global__ void prep_w_kernel(const float* __restrict__ W, u16* __restrict__ Wp, int O) {
    int i = blockIdx.x * blockDim.x + threadIdx.x;
    if (i >= O * 384) return;
    int o = i / 384, k = i % 384;
    Wp[i] = f2bf(w_fold(W, o, k));
}

// MFMA-fragment-packed W', all 4 weights in one launch.
__global__ void prep_w2_all_kernel(const float* __restrict__ Wa, const float* __restrict__ Wb,
                                   const float* __restrict__ Wc, const float* __restrict__ Wd,
                                   u16* __restrict__ Pa, u16* __restrict__ Pb,
                                   u16* __restrict__ Pc, u16* __restrict__ Pd) {
    int i = blockIdx.x * blockDim.x + threadIdx.x;   // 3*6144 + 3072 = 21504 units
    const float* W; u16* P; int il;
    if (i < 6144)       { W = Wa; P = Pa; il = i; }
    else if (i < 12288) { W = Wb; P = Pb; il = i - 6144; }
    else if (i < 18432) { W = Wc; P = Pc; il = i - 12288; }
    else if (i < 21504) { W = Wd; P = Pd; il = i - 18432; }
    else return;
    int ot = il / 768;
    int rem = il % 768;
    int kk = rem / 64;
    int l = rem % 64;
    int q = l >> 4, r = l & 15;
    int o = ot * 16 + r;
    int kbase = kk * 32 + q * 8;
#pragma unroll
    for (int j = 0; j < 8; ++j)
        P[(size_t)il * 8 + j] = f2bf(w_fold(W, o, kbase + j));
}

// -------- x (f32) -> bf16, 4 elems per thread ----------

__global__ void cvt_kernel(const float* __restrict__ x, u16* __restrict__ y) {
    int i = blockIdx.x * blockDim.x + threadIdx.x;
    if (i >= N_NODES * FEAT / 4) return;
    float4 v = ((const float4*)x)[i];
    ushort4 o;
    o.x = f2bf(v.x); o.y = f2bf(v.y); o.z = f2bf(v.z); o.w = f2bf(v.w);
    ((ushort4*)y)[i] = o;
}

// -------- branch-free register gather primitives --------------------------

__device__ __forceinline__ void load_meta(const int2* __restrict__ ecw, int s, int n,
                                          int lane, int& call, float& wall) {
    int idx = s + max(0, min(lane, n - 1));       // clamp: branch-free
    idx = min(idx, N_EDGES - 1);                  // deg-0 last-row guard
    int2 cw = ecw[idx];
    call = cw.x;
    wall = (lane < n) ? __int_as_float(cw.y) : 0.f;   // cndmask, no branch
}

__device__ __forceinline__ void issue_row(const u16* __restrict__ X, int call,
                                          int g, int f, bf16x8* q) {
#pragma unroll
    for (int k = 0; k < NL; ++k) {
        int col = __shfl(call, k * 4 + g);
        q[k] = *(const bf16x8*)(X + (size_t)col * FEAT + f * 8);
    }
}

__device__ __forceinline__ void reduce_row(const bf16x8* q, float wall,
                                           int g, float* acc) {
#pragma unroll
    for (int k = 0; k < NL; ++k) {
        float wj = __shfl(wall, k * 4 + g);
#pragma unroll
        for (int j = 0; j < 8; ++j) acc[j] += wj * bf2f((u16)q[k][j]);
    }
}

// -------- SpMM v3 (proven best, round 8): ONE ROW PER WAVE ----------------
// At the confirmed per-CU miss-tracking cap (~3.75 TB/s), this is the
// highest-BW configuration measured (56.3 us/pass).

__global__ __launch_bounds__(256) void spmm1_kernel(const int* __restrict__ row_ptr,
                                                    const int2* __restrict__ ecw,
                                                    const u16* __restrict__ X,
                                                    u16* __restrict__ Y) {
    int lane = threadIdx.x & 63;
    int g = lane >> 4, f = lane & 15;
    int rr = (blockIdx.x * blockDim.x + threadIdx.x) >> 6;   // 1 row per wave

    int s = row_ptr[rr], e = row_ptr[rr + 1];
    float acc[8];
#pragma unroll
    for (int j = 0; j < 8; ++j) acc[j] = 0.f;

    {   // main chunk (covers 98% of Poisson-16 rows entirely)
        int call; float wall;
        load_meta(ecw, s, min(e - s, CAP), lane, call, wall);
        bf16x8 q[NL];
        issue_row(X, call, g, f, q);
        reduce_row(q, wall, g, acc);
    }
    for (int cs = s + CAP; cs < e; cs += CAP) {   // rare tail (deg > 24)
        int c2; float w2;
        load_meta(ecw, cs, min(e - cs, CAP), lane, c2, w2);
        bf16x8 qt[NL];
        issue_row(X, c2, g, f, qt);
        reduce_row(qt, w2, g, acc);
    }

#pragma unroll
    for (int j = 0; j < 8; ++j) {
        acc[j] += __shfl_xor(acc[j], 16);
        acc[j] += __shfl_xor(acc[j], 32);
    }
    if (g == 0) {
        u16 tmp[8];
#pragma unroll
        for (int j = 0; j < 8; ++j) tmp[j] = f2bf(acc[j]);
        *(bf16x8*)(Y + (size_t)rr * FEAT + f * 8) = *(const bf16x8*)tmp;
    }
}

// -------- gather4 (fallback fused path only) ------------------------------

__device__ __forceinline__ void gather4(const int* __restrict__ row_ptr,
                                        const int2* __restrict__ ecw,
                                        const u16* __restrict__ X,
                                        int r0, int lane, int g, int f,
                                        float acc[4][8]) {
    int s[4], e[4];
    int call[4]; float wall[4];
#pragma unroll
    for (int y = 0; y < 4; ++y) {
        s[y] = row_ptr[r0 + y];
        e[y] = row_ptr[r0 + y + 1];
    }
#pragma unroll
    for (int y = 0; y < 4; ++y)
        load_meta(ecw, s[y], min(e[y] - s[y], CAP), lane, call[y], wall[y]);
#pragma unroll
    for (int y = 0; y < 4; ++y)
#pragma unroll
        for (int j = 0; j < 8; ++j) acc[y][j] = 0.f;

    bf16x8 q0[NL], q1[NL], q2[NL], q3[NL];
    issue_row(X, call[0], g, f, q0);
    issue_row(X, call[1], g, f, q1);
    reduce_row(q0, wall[0], g, acc[0]);
    issue_row(X, call[2], g, f, q2);
    reduce_row(q1, wall[1], g, acc[1]);
    issue_row(X, call[3], g, f, q3);
    reduce_row(q2, wall[2], g, acc[2]);
    reduce_row(q3, wall[3], g, acc[3]);

#pragma unroll
    for (int y = 0; y < 4; ++y) {
        for (int cs = s[y] + CAP; cs < e[y]; cs += CAP) {
            int c2; float w2;
            load_meta(ecw, cs, min(e[y] - cs, CAP), lane, c2, w2);
            bf16x8 qt[NL];
            issue_row(X, c2, g, f, qt);
            reduce_row(qt, w2, g, acc[y]);
        }
    }

#pragma unroll
    for (int y = 0; y < 4; ++y)
#pragma unroll
        for (int j = 0; j < 8; ++j) {
            acc[y][j] += __shfl_xor(acc[y][j], 16);
            acc[y][j] += __shfl_xor(acc[y][j], 32);
        }
}

// legacy 4-rows-per-wave spmm (fallback path)
__global__ __launch_bounds__(256) void spmm_kernel(const int* __restrict__ row_ptr,
                                                   const int2* __restrict__ ecw,
                                                   const u16* __restrict__ X,
                                                   u16* __restrict__ Y) {
    int wid = threadIdx.x >> 6;
    int lane = threadIdx.x & 63;
    int g = lane >> 4, f = lane & 15;
    int r0 = blockIdx.x * 16 + wid * 4;

    float acc[4][8];
    gather4(row_ptr, ecw, X, r0, lane, g, f, acc);

    if (g == 0) {
#pragma unroll
        for (int y = 0; y < 4; ++y) {
            u16 tmp[8];
#pragma unroll
            for (int j = 0; j < 8; ++j) tmp[j] = f2bf(acc[y][j]);
            *(bf16x8*)(Y + (size_t)(r0 + y) * FEAT + f * 8) = *(const bf16x8*)tmp;
        }
    }
}

// ------- streaming GEMM v2 (proven best, round 8): LDS-staged 32-row A tile,
//         fragment-packed Wp2.

template <int O, bool RELU, bool RES, bool OUT_F32>
__global__ __launch_bounds__(256) void gemm_kernel(const u16* __restrict__ H,
                                                   const u16* __restrict__ T1,
                                                   const u16* __restrict__ S2,
                                                   const u16* __restrict__ Wp2,
                                                   const float* __restrict__ bias,
                                                   void* __restrict__ outv) {
    __shared__ __align__(16) u16 sA[3][32][LDS_PITCH];    // 25.5 KB
    int tid = threadIdx.x;
    int m0 = blockIdx.x * 32;                             // N_NODES % 32 == 0

#pragma unroll
    for (int p = 0; p < 3; ++p) {
        const u16* sp = (p == 0) ? H : (p == 1) ? T1 : S2;
#pragma unroll
        for (int u = 0; u < 2; ++u) {
            int unit = u * 256 + tid;
            int row = unit >> 4, seg = unit & 15;
            *(bf16x8*)&sA[p][row][seg * 8] =
                *(const bf16x8*)(sp + (size_t)(m0 + row) * FEAT + seg * 8);
        }
    }
    __syncthreads();

    int lane = tid & 63, wid = tid >> 6;
    int r = lane & 15, q = lane >> 4;
    constexpr int NW = O / 64;          // 2 for O=128, 1 for O=64
    f32x4 acc0[NW], acc1[NW];
#pragma unroll
    for (int t = 0; t < NW; ++t) {
        acc0[t] = (f32x4){0.f, 0.f, 0.f, 0.f};
        acc1[t] = (f32x4){0.f, 0.f, 0.f, 0.f};
    }

#pragma unroll
    for (int kk = 0; kk < 12; ++kk) {
        int p = kk >> 2, ko = kk & 3;
        bf16x8 af0 = *(const bf16x8*)&sA[p][r][ko * 32 + q * 8];
        bf16x8 af1 = *(const bf16x8*)&sA[p][16 + r][ko * 32 + q * 8];
#pragma unroll
        for (int t = 0; t < NW; ++t) {
            int ot = wid * NW + t;
            bf16x8 bfr = *(const bf16x8*)(Wp2 + ((size_t)(ot * 12 + kk) * 64 + lane) * 8);
            acc0[t] = __builtin_amdgcn_mfma_f32_16x16x32_bf16(af0, bfr, acc0[t], 0, 0, 0);
            acc1[t] = __builtin_amdgcn_mfma_f32_16x16x32_bf16(af1, bfr, acc1[t], 0, 0, 0);
        }
    }

#pragma unroll
    for (int t = 0; t < NW; ++t) {
        int col = (wid * NW + t) * 16 + r;
        float bv = bias[col];
#pragma unroll
        for (int i = 0; i < 4; ++i) {
            int lrow = q * 4 + i;
            float v0 = acc0[t][i] + bv;
            if (RES)  v0 += bf2f(sA[0][lrow][col]);
            if (RELU) v0 = fmaxf(v0, 0.f);
            float v1 = acc1[t][i] + bv;
            if (RES)  v1 += bf2f(sA[0][16 + lrow][col]);
            if (RELU) v1 = fmaxf(v1, 0.f);
            if (OUT_F32) {
                ((float*)outv)[(size_t)(m0 + lrow) * O + col] = v0;
                ((float*)outv)[(size_t)(m0 + 16 + lrow) * O + col] = v1;
            } else {
                ((u16*)outv)[(size_t)(m0 + lrow) * O + col] = f2bf(v0);
                ((u16*)outv)[(size_t)(m0 + 16 + lrow) * O + col] = f2bf(v1);
            }
        }
    }
}

// ------- fallback fused kernel (ws too small for split path) ---------------

template <int O, bool RELU, bool RES, bool OUT_F32>
__global__ __launch_bounds__(256) void fused_gemm_kernel(const int* __restrict__ row_ptr,
                                                         const int2* __restrict__ ecw,
                                                         const u16* __restrict__ H,
                                                         const u16* __restrict__ T1,
                                                         const u16* __restrict__ Wp,
                                                         const float* __restrict__ bias,
                                                         void* __restrict__ outv) {
    __shared__ __align__(16) u16 sT[16 * LDS_PITCH];
    int wid = threadIdx.x >> 6;
    int lane = threadIdx.x & 63;
    int g = lane >> 4, f = lane & 15;
    int m0 = blockIdx.x * 16;

    {
        float acc[4][8];
        gather4(row_ptr, ecw, T1, m0 + wid * 4, lane, g, f, acc);
        if (g == 0) {
#pragma unroll
            for (int y = 0; y < 4; ++y) {
                u16 tmp[8];
#pragma unroll
                for (int j = 0; j < 8; ++j) tmp[j] = f2bf(acc[y][j]);
                *(bf16x8*)(sT + (wid * 4 + y) * LDS_PITCH + f * 8) = *(const bf16x8*)tmp;
            }
        }
    }
    __syncthreads();

    int r = f, q = g;
    constexpr int NT = O / 16;
    constexpr int NW = NT / 4;
    f32x4 acc[NW];
#pragma unroll
    for (int t = 0; t < NW; ++t) acc[t] = (f32x4){0.f, 0.f, 0.f, 0.f};

#pragma unroll
    for (int kk = 0; kk < 12; ++kk) {
        bf16x8 af;
        if (kk < 4)
            af = *(const bf16x8*)(H + (size_t)(m0 + r) * FEAT + kk * 32 + q * 8);
        else if (kk < 8)
            af = *(const bf16x8*)(T1 + (size_t)(m0 + r) * FEAT + (kk - 4) * 32 + q * 8);
        else
            af = *(const bf16x8*)(sT + r * LDS_PITCH + (kk - 8) * 32 + q * 8);
#pragma unroll
        for (int t = 0; t < NW; ++t) {
            int ot = wid * NW + t;
            bf16x8 bfr = *(const bf16x8*)(Wp + (size_t)(ot * 16 + r) * 384 + kk * 32 + q * 8);
            acc[t] = __builtin_amdgcn_mfma_f32_16x16x32_bf16(af, bfr, acc[t], 0, 0, 0);
        }
    }

#pragma unroll
    for (int t = 0; t < NW; ++t) {
        int col = (wid * NW + t) * 16 + r;
        float bv = bias[col];
#pragma unroll
        for (int i = 0; i < 4; ++i) {
            int row = m0 + q * 4 + i;
            float v = acc[t][i] + bv;
            if (RES)  v += bf2f(H[(size_t)row * FEAT + col]);
            if (RELU) v = fmaxf(v, 0.f);
            if (OUT_F32) ((float*)outv)[(size_t)row * O + col] = v;
            else         ((u16*)outv)[(size_t)row * O + col] = f2bf(v);
        }
    }
}

// ---------------- launcher ----------------

static inline size_t align_up(size_t x) { return (x + 255) & ~(size_t)255; }

extern "C" void kernel_launch(void* const* d_in, const int* in_sizes, int n_in,
                              void* d_out, int out_size, void* d_ws, size_t ws_size,
                              hipStream_t stream) {
    const float* x     = (const float*)d_in[0];
    const int*   ei    = (const int*)d_in[1];
    const float* ew    = (const float*)d_in[2];
    const float* W_in  = (const float*)d_in[3];
    const float* b_in  = (const float*)d_in[4];
    const float* W_h1  = (const float*)d_in[5];
    const float* b_h1  = (const float*)d_in[6];
    const float* W_h2  = (const float*)d_in[7];
    const float* b_h2  = (const float*)d_in[8];
    const float* W_out = (const float*)d_in[9];
    const float* b_out = (const float*)d_in[10];

    const int* rows = ei;
    const int* cols = ei + N_EDGES;

    // workspace layout
    char* w = (char*)d_ws;
    size_t off = 0;
    int* counts = (int*)(w + off);            off = align_up(off + (size_t)N_NODES * 4);   // fallback fill
    int* row_ptr= (int*)(w + off);            off = align_up(off + (size_t)(N_NODES + 1) * 4);
    int* bsum   = (int*)(w + off);            off = align_up(off + 512 * 4);               // NBKT+1 fits
    int2* ecw   = (int2*)(w + off);           off = align_up(off + (size_t)N_EDGES * 8);
    u16* t1     = (u16*)(w + off);            off = align_up(off + (size_t)N_NODES * FEAT * 2);
    u16* h      = (u16*)(w + off);            off = align_up(off + (size_t)N_NODES * FEAT * 2);
    u16* Wp_in  = (u16*)(w + off);            off = align_up(off + (size_t)128 * 384 * 2);
    u16* Wp_h1  = (u16*)(w + off);            off = align_up(off + (size_t)128 * 384 * 2);
    u16* Wp_h2  = (u16*)(w + off);            off = align_up(off + (size_t)128 * 384 * 2);
    u16* Wp_out = (u16*)(w + off);            off = align_up(off + (size_t)64 * 384 * 2);
    // split path: s2 buffer (doubles as ebuf during CSR build), fragment-packed
    // weights, deterministic CSR counters
    u16* s2     = (u16*)(w + off);            size_t off2 = align_up(off + (size_t)N_NODES * FEAT * 2);
    u16* W2_in  = (u16*)(w + off2);           off2 = align_up(off2 + (size_t)128 * 384 * 2);
    u16* W2_h1  = (u16*)(w + off2);           off2 = align_up(off2 + (size_t)128 * 384 * 2);
    u16* W2_h2  = (u16*)(w + off2);           off2 = align_up(off2 + (size_t)128 * 384 * 2);
    u16* W2_out = (u16*)(w + off2);           off2 = align_up(off2 + (size_t)64 * 384 * 2);
    int* pcnt   = (int*)(w + off2);           off2 = align_up(off2 + (size_t)NBLK * NBKT * 4);
    int* gtot   = (int*)(w + off2);           off2 = align_up(off2 + (size_t)NBKT * 4);
    const bool use_split = (ws_size >= off2);
    static_assert((size_t)N_EDGES * 8 <= (size_t)N_NODES * FEAT * 2, "ebuf exceeds s2");

    cvt_kernel<<<(N_NODES * FEAT / 4 + 255) / 256, 256, 0, stream>>>(x, h);

    const int grid16 = N_NODES / 16;         // 6250 blocks (fallback)
    const int grid32 = N_NODES / 32;         // 3125 blocks: 32-row gemm tiles
    const int grid1  = N_NODES * 64 / 256;   // 25000 blocks: 1 row per wave

    if (use_split) {
        // CSR build v4: deterministic, zero global atomics, write-merged
        int2* ebuf = (int2*)s2;
        csr_passA_kernel<<<NBLK, 256, 0, stream>>>(rows, pcnt);
        csr_scanP_kernel<<<NBKT, 256, 0, stream>>>(pcnt, gtot);
        csr_scanG_kernel<<<1, 512, 0, stream>>>(gtot, bsum, row_ptr);
        csr_passB_kernel<<<NBLK, 256, 0, stream>>>(rows, cols, ew, pcnt, bsum, ebuf);
        csr_finalize_kernel<<<NBKT, 256, 0, stream>>>(bsum, ebuf, row_ptr, ecw);

        prep_w2_all_kernel<<<(21504 + 255) / 256, 256, 0, stream>>>(
            W_in, W_h1, W_h2, W_out, W2_in, W2_h1, W2_h2, W2_out);

        // Layer 1
        spmm1_kernel<<<grid1, 256, 0, stream>>>(row_ptr, ecw, h, t1);
        spmm1_kernel<<<grid1, 256, 0, stream>>>(row_ptr, ecw, t1, s2);
        gemm_kernel<128, true, false, false><<<grid32, 256, 0, stream>>>(h, t1, s2, W2_in, b_in, h);
        // Layer 2
        spmm1_kernel<<<grid1, 256, 0, stream>>>(row_ptr, ecw, h, t1);
        spmm1_kernel<<<grid1, 256, 0, stream>>>(row_ptr, ecw, t1, s2);
        gemm_kernel<128, true, true, false><<<grid32, 256, 0, stream>>>(h, t1, s2, W2_h1, b_h1, h);
        // Layer 3
        spmm1_kernel<<<grid1, 256, 0, stream>>>(row_ptr, ecw, h, t1);
        spmm1_kernel<<<grid1, 256, 0, stream>>>(row_ptr, ecw, t1, s2);
        gemm_kernel<128, true, true, false><<<grid32, 256, 0, stream>>>(h, t1, s2, W2_h2, b_h2, h);
        // Layer 4 (O=64, f32 out)
        spmm1_kernel<<<grid1, 256, 0, stream>>>(row_ptr, ecw, h, t1);
        spmm1_kernel<<<grid1, 256, 0, stream>>>(row_ptr, ecw, t1, s2);
        gemm_kernel<64, false, false, true><<<grid32, 256, 0, stream>>>(h, t1, s2, W2_out, b_out, d_out);
    } else {
        // fallback: legacy CSR build + fused path
        hipMemsetAsync(counts, 0, (size_t)N_NODES * 4, stream);
        hist_kernel<<<N_EDGES / 256, 256, 0, stream>>>(rows, counts);
        reduce_counts_kernel<<<NB_SCAN, 256, 0, stream>>>(counts, bsum);
        scan_bsums_kernel<<<1, 512, 0, stream>>>(bsum, row_ptr);
        write_rowptr_kernel<<<NB_SCAN, 256, 0, stream>>>(counts, bsum, row_ptr);
        scatter_kernel<<<N_EDGES / 256, 256, 0, stream>>>(rows, cols, ew, row_ptr, counts, ecw);

        prep_w_kernel<<<(128 * 384 + 255) / 256, 256, 0, stream>>>(W_in, Wp_in, 128);
        prep_w_kernel<<<(128 * 384 + 255) / 256, 256, 0, stream>>>(W_h1, Wp_h1, 128);
        prep_w_kernel<<<(128 * 384 + 255) / 256, 256, 0, stream>>>(W_h2, Wp_h2, 128);
        prep_w_kernel<<<(64 * 384 + 255) / 256, 256, 0, stream>>>(W_out, Wp_out, 64);

        spmm_kernel<<<grid16, 256, 0, stream>>>(row_ptr, ecw, h, t1);
        fused_gemm_kernel<128, true, false, false><<<grid16, 256, 0, stream>>>(
            row_ptr, ecw, h, t1, Wp_in, b_in, h);
        spmm_kernel<<<grid16, 256, 0, stream>>>(row_ptr, ecw, h, t1);
        fused_gemm_kernel<128, true, true, false><<<grid16, 256, 0, stream>>>(
            row_ptr, ecw, h, t1, Wp_h1, b_h1, h);
        spmm_kernel<<<grid16, 256, 0, stream>>>(row_ptr, ecw, h, t1);
        fused_gemm_kernel<128, true, true, false><<<grid16, 256, 0, stream>>>(
            row_ptr, ecw, h, t1, Wp_h2, b_h2, h);
        spmm_kernel<<<grid16, 256, 0, stream>>>(row_ptr, ecw, h, t1);
        fused_gemm_kernel<64, false, false, true><<<grid16, 256, 0, stream>>>(
            row_ptr, ecw, h, t1, Wp_out, b_out, d_out);
    }
}

// Round 12
// 676.101 us; speedup vs baseline: 1.1651x; 1.0365x over previous
//
#include <hip/hip_runtime.h>
#include <hip/hip_bf16.h>
#include <stdint.h>
#include <stddef.h>

#define N_NODES 100000
#define N_EDGES 1600000
#define FEAT 128
#define NB_SCAN ((N_NODES + 255) / 256)   // 391 blocks of 256 for the scan
#define LDS_PITCH 136                     // u16; 272 B/row: uniform bank spread for b128
#define CAP 24                            // edges per gather chunk
#define NL (CAP / 4)                      // 6 load instructions per chunk (128-wide gather)
#define NL64 (CAP / 8)                    // 3 load instructions per chunk (64-wide gather)
#define NBKT ((N_NODES + 255) / 256)      // 391 row-buckets of 256 rows
#define EPB 2048                          // edges per CSR block
#define NBLK ((N_EDGES + EPB - 1) / EPB)  // 782 CSR blocks
#define EPT (EPB / 256)                   // 8 edges per thread

typedef __attribute__((ext_vector_type(8))) short bf16x8;
typedef __attribute__((ext_vector_type(4))) float f32x4;
typedef unsigned short u16;

__device__ __forceinline__ float bf2f(u16 u) {
    union { unsigned int i; float f; } v; v.i = ((unsigned int)u) << 16; return v.f;
}
__device__ __forceinline__ u16 f2bf(float f) {
    union { float f; unsigned int i; } v; v.f = f;
    unsigned int x = v.i;
    return (u16)((x + 0x7fffu + ((x >> 16) & 1u)) >> 16);   // round-nearest-even
}

// ---------------- CSR build: legacy kernels (fallback path) ----------------

__global__ void hist_kernel(const int* __restrict__ rows, int* __restrict__ counts) {
    int e = blockIdx.x * blockDim.x + threadIdx.x;
    if (e < N_EDGES) {
        int r = rows[e];
        r = min(max(r, 0), N_NODES - 1);
        atomicAdd(&counts[r], 1);
    }
}

__global__ void reduce_counts_kernel(const int* __restrict__ counts, int* __restrict__ bsum) {
    __shared__ int s[256];
    int i = blockIdx.x * 256 + threadIdx.x;
    int v = (i < N_NODES) ? counts[i] : 0;
    s[threadIdx.x] = v; __syncthreads();
    for (int off = 128; off > 0; off >>= 1) {
        if (threadIdx.x < off) s[threadIdx.x] += s[threadIdx.x + off];
        __syncthreads();
    }
    if (threadIdx.x == 0) bsum[blockIdx.x] = s[0];
}

__global__ void scan_bsums_kernel(int* __restrict__ bsum, int* __restrict__ row_ptr) {
    __shared__ int s[512];
    int t = threadIdx.x;
    int v = (t < NB_SCAN) ? bsum[t] : 0;
    s[t] = v; __syncthreads();
    for (int off = 1; off < 512; off <<= 1) {
        int x = (t >= off) ? s[t - off] : 0;
        __syncthreads();
        s[t] += x;
        __syncthreads();
    }
    if (t < NB_SCAN) bsum[t] = s[t] - v;              // exclusive
    if (t == NB_SCAN - 1) row_ptr[N_NODES] = s[t];    // total (= N_EDGES)
}

// also zeroes counts so it can be reused as the scatter fill array
__global__ void write_rowptr_kernel(int* __restrict__ counts, const int* __restrict__ bsum,
                                    int* __restrict__ row_ptr) {
    __shared__ int s[256];
    int i = blockIdx.x * 256 + threadIdx.x;
    int v = (i < N_NODES) ? counts[i] : 0;
    s[threadIdx.x] = v; __syncthreads();
    for (int off = 1; off < 256; off <<= 1) {
        int x = (threadIdx.x >= off) ? s[threadIdx.x - off] : 0;
        __syncthreads();
        s[threadIdx.x] += x;
        __syncthreads();
    }
    if (i < N_NODES) {
        row_ptr[i] = bsum[blockIdx.x] + s[threadIdx.x] - v;  // exclusive
        counts[i] = 0;                                       // becomes fill[]
    }
}

// legacy random scatter (fallback path only)
__global__ void scatter_kernel(const int* __restrict__ rows, const int* __restrict__ cols,
                               const float* __restrict__ w, const int* __restrict__ row_ptr,
                               int* __restrict__ fill, int2* __restrict__ ecw) {
    int e = blockIdx.x * blockDim.x + threadIdx.x;
    if (e < N_EDGES) {
        int r = rows[e];
        r = min(max(r, 0), N_NODES - 1);
        int pos = row_ptr[r] + atomicAdd(&fill[r], 1);
        pos = min(max(pos, 0), N_EDGES - 1);
        int c = cols[e];
        c = min(max(c, 0), N_NODES - 1);
        ecw[pos] = make_int2(c, __float_as_int(w[e]));
    }
}

// ---------------- CSR build v4: deterministic, zero global atomics ---------

__global__ __launch_bounds__(256) void csr_passA_kernel(const int* __restrict__ rows,
                                                        int* __restrict__ pcnt) {
    __shared__ int s_cnt[NBKT];
    int tid = threadIdx.x, blk = blockIdx.x;
    for (int b = tid; b < NBKT; b += 256) s_cnt[b] = 0;
    __syncthreads();
    int e0 = blk * EPB;
#pragma unroll
    for (int it = 0; it < EPT; ++it) {
        int e = e0 + it * 256 + tid;
        if (e < N_EDGES) {
            int r = min(max(rows[e], 0), N_NODES - 1);
            atomicAdd(&s_cnt[r >> 8], 1);
        }
    }
    __syncthreads();
    for (int b = tid; b < NBKT; b += 256)
        pcnt[(size_t)blk * NBKT + b] = s_cnt[b];      // coalesced 1.5 KB store
}

__global__ __launch_bounds__(256) void csr_scanP_kernel(int* __restrict__ pcnt,
                                                        int* __restrict__ gtot) {
    __shared__ int s[256];
    int b = blockIdx.x, tid = threadIdx.x;
    int carry = 0;
    for (int c = 0; c < (NBLK + 255) / 256; ++c) {
        int idx = c * 256 + tid;
        int v = (idx < NBLK) ? pcnt[(size_t)idx * NBKT + b] : 0;
        s[tid] = v; __syncthreads();
        for (int off = 1; off < 256; off <<= 1) {
            int x = (tid >= off) ? s[tid - off] : 0;
            __syncthreads();
            s[tid] += x;
            __syncthreads();
        }
        if (idx < NBLK) pcnt[(size_t)idx * NBKT + b] = carry + s[tid] - v;  // exclusive
        carry += s[255];
        __syncthreads();
    }
    if (tid == 0) gtot[b] = carry;
}

__global__ void csr_scanG_kernel(const int* __restrict__ gtot, int* __restrict__ bsum,
                                 int* __restrict__ row_ptr) {
    __shared__ int s[512];
    int t = threadIdx.x;
    int v = (t < NBKT) ? gtot[t] : 0;
    s[t] = v; __syncthreads();
    for (int off = 1; off < 512; off <<= 1) {
        int x = (t >= off) ? s[t - off] : 0;
        __syncthreads();
        s[t] += x;
        __syncthreads();
    }
    if (t < NBKT) bsum[t] = s[t] - v;                 // exclusive bucket base
    if (t == NBKT - 1) {
        bsum[NBKT] = s[t];                            // total
        row_ptr[N_NODES] = s[t];
    }
}

__global__ __launch_bounds__(256) void csr_passB_kernel(const int* __restrict__ rows,
                                                        const int* __restrict__ cols,
                                                        const float* __restrict__ w,
                                                        const int* __restrict__ pcnt,
                                                        const int* __restrict__ bsum,
                                                        int2* __restrict__ ebuf) {
    __shared__ int s_base[NBKT];      // global dest base per bucket for this block
    __shared__ int s_cnt[NBKT];       // hist, then fill
    __shared__ int s_off[NBKT];       // exclusive offsets in sorted LDS array
    __shared__ int s_scan[512];
    __shared__ int2 s_sorted[EPB];    // 16 KB payload sorted by bucket
    __shared__ int s_dst[EPB];        // 8 KB destination slots
    int tid = threadIdx.x, blk = blockIdx.x;
    for (int b = tid; b < NBKT; b += 256) {
        s_base[b] = bsum[b] + pcnt[(size_t)blk * NBKT + b];
        s_cnt[b] = 0;
    }
    __syncthreads();
    int e0 = blk * EPB;
    int n = min(N_EDGES - e0, EPB);

    int2 pay[EPT]; int pb[EPT];
#pragma unroll
    for (int it = 0; it < EPT; ++it) {
        int e = e0 + it * 256 + tid;
        if (e < N_EDGES) {
            int r = min(max(rows[e], 0), N_NODES - 1);
            int c = min(max(cols[e], 0), N_NODES - 1);
            pay[it] = make_int2(c | ((r & 255) << 20), __float_as_int(w[e]));
            pb[it] = r >> 8;
            atomicAdd(&s_cnt[pb[it]], 1);
        } else {
            pb[it] = -1;
        }
    }
    __syncthreads();
    s_scan[tid] = (tid < NBKT) ? s_cnt[tid] : 0;
    s_scan[tid + 256] = (tid + 256 < NBKT) ? s_cnt[tid + 256] : 0;
    __syncthreads();
    for (int off = 1; off < 512; off <<= 1) {
        int a = (tid >= off) ? s_scan[tid - off] : 0;
        int b2 = (tid + 256 >= off) ? s_scan[tid + 256 - off] : 0;
        __syncthreads();
        s_scan[tid] += a;
        s_scan[tid + 256] += b2;
        __syncthreads();
    }
    for (int b = tid; b < NBKT; b += 256) {
        s_off[b] = s_scan[b] - s_cnt[b];
        s_cnt[b] = 0;                                  // becomes fill counter
    }
    __syncthreads();
#pragma unroll
    for (int it = 0; it < EPT; ++it) {
        if (pb[it] >= 0) {
            int k = atomicAdd(&s_cnt[pb[it]], 1);
            int slot = s_off[pb[it]] + k;
            s_sorted[slot] = pay[it];
            s_dst[slot] = s_base[pb[it]] + k;
        }
    }
    __syncthreads();
    for (int p = tid; p < n; p += 256)
        ebuf[s_dst[p]] = s_sorted[p];
}

__global__ __launch_bounds__(256) void csr_finalize_kernel(const int* __restrict__ bsum,
                                                           const int2* __restrict__ ebuf,
                                                           int* __restrict__ row_ptr,
                                                           int2* __restrict__ ecw) {
    __shared__ int s_cnt[256];
    __shared__ int s_pos[256];
    int b = blockIdx.x, tid = threadIdx.x;
    int base = bsum[b];
    int cnt = bsum[b + 1] - base;
    s_cnt[tid] = 0; __syncthreads();
    for (int i = tid; i < cnt; i += 256)
        atomicAdd(&s_cnt[ebuf[base + i].x >> 20], 1);
    __syncthreads();
    int v = s_cnt[tid];
    s_pos[tid] = v; __syncthreads();
    for (int off = 1; off < 256; off <<= 1) {
        int x = (tid >= off) ? s_pos[tid - off] : 0;
        __syncthreads();
        s_pos[tid] += x;
        __syncthreads();
    }
    int excl = s_pos[tid] - v;
    int r = b * 256 + tid;
    if (r < N_NODES) row_ptr[r] = base + excl;
    s_cnt[tid] = excl;                                 // running fill
    __syncthreads();
    for (int i = tid; i < cnt; i += 256) {
        int2 p = ebuf[base + i];
        int rl = p.x >> 20;
        int pos = base + atomicAdd(&s_cnt[rl], 1);
        pos = min(max(pos, 0), N_EDGES - 1);
        ecw[pos] = make_int2(p.x & 0xFFFFF, p.y);
    }
}

// -------- weight prep ------------------------------------------------------
__device__ __forceinline__ float w_fold(const float* W, int o, int k) {
    if (k < 128)      return W[o * 384 + k] - W[o * 384 + 256 + k];
    else if (k < 256) return W[o * 384 + k];
    else              return 2.0f * W[o * 384 + k];
}

__global__ void prep_w_kernel(const float* __restrict__ W, u16* __restrict__ Wp, int O) {
    int i = blockIdx.x * blockDim.x + threadIdx.x;
    if (i >= O * 384) return;
    int o = i / 384, k = i % 384;
    Wp[i] = f2bf(w_fold(W, o, k));
}

// MFMA-fragment-packed W' (K=384) for the 3 hidden layers, one launch.
__global__ void prep_w2_all_kernel(const float* __restrict__ Wa, const float* __restrict__ Wb,
                                   const float* __restrict__ Wc,
                                   u16* __restrict__ Pa, u16* __restrict__ Pb,
                                   u16* __restrict__ Pc) {
    int i = blockIdx.x * blockDim.x + threadIdx.x;   // 3*6144 = 18432 units
    const float* W; u16* P; int il;
    if (i < 6144)       { W = Wa; P = Pa; il = i; }
    else if (i < 12288) { W = Wb; P = Pb; il = i - 6144; }
    else if (i < 18432) { W = Wc; P = Pc; il = i - 12288; }
    else return;
    int ot = il / 768;
    int rem = il % 768;
    int kk = rem / 64;
    int l = rem % 64;
    int q = l >> 4, r = l & 15;
    int o = ot * 16 + r;
    int kbase = kk * 32 + q * 8;
#pragma unroll
    for (int j = 0; j < 8; ++j)
        P[(size_t)il * 8 + j] = f2bf(w_fold(W, o, kbase + j));
}

// Layer-4 associativity weights (K=128 fragpack, unit = (ot*4+kk)*64+lane):
//   Pab (O=128): cols 0..63 = W_out[o][128+k]  (W1 term -> 'a')
//                cols 64..127 = 2*W_out[o-64][256+k]  (2*W2 term -> 'b')
//   Pf  (O=64):  W_out[o][k] - W_out[o][256+k]  (W0 - W2 term)
__global__ void prep_w4_kernel(const float* __restrict__ Wo,
                               u16* __restrict__ Pab, u16* __restrict__ Pf) {
    int i = blockIdx.x * blockDim.x + threadIdx.x;   // 2048 + 1024 = 3072 units
    if (i >= 3072) return;
    u16* P; int il; bool is_ab;
    if (i < 2048) { P = Pab; il = i; is_ab = true; }
    else          { P = Pf;  il = i - 2048; is_ab = false; }
    int ot = il / 256;           // 4 kk * 64 lanes
    int rem = il % 256;
    int kk = rem / 64;
    int l = rem % 64;
    int q = l >> 4, r = l & 15;
    int o = ot * 16 + r;
    int kbase = kk * 32 + q * 8;
#pragma unroll
    for (int j = 0; j < 8; ++j) {
        int k = kbase + j;
        float v;
        if (is_ab) {
            if (o < 64) v = Wo[o * 384 + 128 + k];
            else        v = 2.0f * Wo[(o - 64) * 384 + 256 + k];
        } else {
            v = Wo[o * 384 + k] - Wo[o * 384 + 256 + k];
        }
        P[(size_t)il * 8 + j] = f2bf(v);
    }
}

// -------- x (f32) -> bf16, 4 elems per thread ----------

__global__ void cvt_kernel(const float* __restrict__ x, u16* __restrict__ y) {
    int i = blockIdx.x * blockDim.x + threadIdx.x;
    if (i >= N_NODES * FEAT / 4) return;
    float4 v = ((const float4*)x)[i];
    ushort4 o;
    o.x = f2bf(v.x); o.y = f2bf(v.y); o.z = f2bf(v.z); o.w = f2bf(v.w);
    ((ushort4*)y)[i] = o;
}

// -------- branch-free register gather primitives --------------------------

__device__ __forceinline__ void load_meta(const int2* __restrict__ ecw, int s, int n,
                                          int lane, int& call, float& wall) {
    int idx = s + max(0, min(lane, n - 1));       // clamp: branch-free
    idx = min(idx, N_EDGES - 1);                  // deg-0 last-row guard
    int2 cw = ecw[idx];
    call = cw.x;
    wall = (lane < n) ? __int_as_float(cw.y) : 0.f;   // cndmask, no branch
}

__device__ __forceinline__ void issue_row(const u16* __restrict__ X, int call,
                                          int g, int f, bf16x8* q) {
#pragma unroll
    for (int k = 0; k < NL; ++k) {
        int col = __shfl(call, k * 4 + g);
        q[k] = *(const bf16x8*)(X + (size_t)col * FEAT + f * 8);
    }
}

__device__ __forceinline__ void reduce_row(const bf16x8* q, float wall,
                                           int g, float* acc) {
#pragma unroll
    for (int k = 0; k < NL; ++k) {
        float wj = __shfl(wall, k * 4 + g);
#pragma unroll
        for (int j = 0; j < 8; ++j) acc[j] += wj * bf2f((u16)q[k][j]);
    }
}

// -------- SpMM v3 (proven best): ONE ROW PER WAVE, 128-wide table ---------

__global__ __launch_bounds__(256) void spmm1_kernel(const int* __restrict__ row_ptr,
                                                    const int2* __restrict__ ecw,
                                                    const u16* __restrict__ X,
                                                    u16* __restrict__ Y) {
    int lane = threadIdx.x & 63;
    int g = lane >> 4, f = lane & 15;
    int rr = (blockIdx.x * blockDim.x + threadIdx.x) >> 6;   // 1 row per wave

    int s = row_ptr[rr], e = row_ptr[rr + 1];
    float acc[8];
#pragma unroll
    for (int j = 0; j < 8; ++j) acc[j] = 0.f;

    {   // main chunk (covers 98% of Poisson-16 rows entirely)
        int call; float wall;
        load_meta(ecw, s, min(e - s, CAP), lane, call, wall);
        bf16x8 q[NL];
        issue_row(X, call, g, f, q);
        reduce_row(q, wall, g, acc);
    }
    for (int cs = s + CAP; cs < e; cs += CAP) {   // rare tail (deg > 24)
        int c2; float w2;
        load_meta(ecw, cs, min(e - cs, CAP), lane, c2, w2);
        bf16x8 qt[NL];
        issue_row(X, c2, g, f, qt);
        reduce_row(qt, w2, g, acc);
    }

#pragma unroll
    for (int j = 0; j < 8; ++j) {
        acc[j] += __shfl_xor(acc[j], 16);
        acc[j] += __shfl_xor(acc[j], 32);
    }
    if (g == 0) {
        u16 tmp[8];
#pragma unroll
        for (int j = 0; j < 8; ++j) tmp[j] = f2bf(acc[j]);
        *(bf16x8*)(Y + (size_t)rr * FEAT + f * 8) = *(const bf16x8*)tmp;
    }
}

// -------- SpMM64: one row/wave over a 64-wide bf16 table (1 line/edge) ----
// lane = g*8+f (g: edge slot 0..7, f: feature octet 0..7). 3 loads/chunk.
// ADD: epilogue adds A[row] (bf16, stride lda) — folds the 'a + S.b' step.

template <bool ADDT>
__global__ __launch_bounds__(256) void spmm64_kernel(const int* __restrict__ row_ptr,
                                                     const int2* __restrict__ ecw,
                                                     const u16* __restrict__ X, int ldx,
                                                     const u16* __restrict__ A, int lda,
                                                     u16* __restrict__ Y, int ldy) {
    int lane = threadIdx.x & 63;
    int g = lane >> 3, f = lane & 7;
    int rr = (blockIdx.x * blockDim.x + threadIdx.x) >> 6;   // 1 row per wave

    int s = row_ptr[rr], e = row_ptr[rr + 1];
    float acc[8];
#pragma unroll
    for (int j = 0; j < 8; ++j) acc[j] = 0.f;

    {
        int call; float wall;
        load_meta(ecw, s, min(e - s, CAP), lane, call, wall);
        bf16x8 q[NL64];
#pragma unroll
        for (int k = 0; k < NL64; ++k) {
            int col = __shfl(call, k * 8 + g);
            q[k] = *(const bf16x8*)(X + (size_t)col * ldx + f * 8);
        }
#pragma unroll
        for (int k = 0; k < NL64; ++k) {
            float wj = __shfl(wall, k * 8 + g);
#pragma unroll
            for (int j = 0; j < 8; ++j) acc[j] += wj * bf2f((u16)q[k][j]);
        }
    }
    for (int cs = s + CAP; cs < e; cs += CAP) {   // rare tail (deg > 24)
        int c2; float w2;
        load_meta(ecw, cs, min(e - cs, CAP), lane, c2, w2);
        bf16x8 qt[NL64];
#pragma unroll
        for (int k = 0; k < NL64; ++k) {
            int col = __shfl(c2, k * 8 + g);
            qt[k] = *(const bf16x8*)(X + (size_t)col * ldx + f * 8);
        }
#pragma unroll
        for (int k = 0; k < NL64; ++k) {
            float wj = __shfl(w2, k * 8 + g);
#pragma unroll
            for (int j = 0; j < 8; ++j) acc[j] += wj * bf2f((u16)qt[k][j]);
        }
    }

#pragma unroll
    for (int j = 0; j < 8; ++j) {
        acc[j] += __shfl_xor(acc[j], 8);
        acc[j] += __shfl_xor(acc[j], 16);
        acc[j] += __shfl_xor(acc[j], 32);
    }
    if (g == 0) {
        if (ADDT) {
            bf16x8 av = *(const bf16x8*)(A + (size_t)rr * lda + f * 8);
#pragma unroll
            for (int j = 0; j < 8; ++j) acc[j] += bf2f((u16)av[j]);
        }
        u16 tmp[8];
#pragma unroll
        for (int j = 0; j < 8; ++j) tmp[j] = f2bf(acc[j]);
        *(bf16x8*)(Y + (size_t)rr * ldy + f * 8) = *(const bf16x8*)tmp;
    }
}

// -------- gather4 (fallback fused path only) ------------------------------

__device__ __forceinline__ void gather4(const int* __restrict__ row_ptr,
                                        const int2* __restrict__ ecw,
                                        const u16* __restrict__ X,
                                        int r0, int lane, int g, int f,
                                        float acc[4][8]) {
    int s[4], e[4];
    int call[4]; float wall[4];
#pragma unroll
    for (int y = 0; y < 4; ++y) {
        s[y] = row_ptr[r0 + y];
        e[y] = row_ptr[r0 + y + 1];
    }
#pragma unroll
    for (int y = 0; y < 4; ++y)
        load_meta(ecw, s[y], min(e[y] - s[y], CAP), lane, call[y], wall[y]);
#pragma unroll
    for (int y = 0; y < 4; ++y)
#pragma unroll
        for (int j = 0; j < 8; ++j) acc[y][j] = 0.f;

    bf16x8 q0[NL], q1[NL], q2[NL], q3[NL];
    issue_row(X, call[0], g, f, q0);
    issue_row(X, call[1], g, f, q1);
    reduce_row(q0, wall[0], g, acc[0]);
    issue_row(X, call[2], g, f, q2);
    reduce_row(q1, wall[1], g, acc[1]);
    issue_row(X, call[3], g, f, q3);
    reduce_row(q2, wall[2], g, acc[2]);
    reduce_row(q3, wall[3], g, acc[3]);

#pragma unroll
    for (int y = 0; y < 4; ++y) {
        for (int cs = s[y] + CAP; cs < e[y]; cs += CAP) {
            int c2; float w2;
            load_meta(ecw, cs, min(e[y] - cs, CAP), lane, c2, w2);
            bf16x8 qt[NL];
            issue_row(X, c2, g, f, qt);
            reduce_row(qt, w2, g, acc[y]);
        }
    }

#pragma unroll
    for (int y = 0; y < 4; ++y)
#pragma unroll
        for (int j = 0; j < 8; ++j) {
            acc[y][j] += __shfl_xor(acc[y][j], 16);
            acc[y][j] += __shfl_xor(acc[y][j], 32);
        }
}

// legacy 4-rows-per-wave spmm (fallback path)
__global__ __launch_bounds__(256) void spmm_kernel(const int* __restrict__ row_ptr,
                                                   const int2* __restrict__ ecw,
                                                   const u16* __restrict__ X,
                                                   u16* __restrict__ Y) {
    int wid = threadIdx.x >> 6;
    int lane = threadIdx.x & 63;
    int g = lane >> 4, f = lane & 15;
    int r0 = blockIdx.x * 16 + wid * 4;

    float acc[4][8];
    gather4(row_ptr, ecw, X, r0, lane, g, f, acc);

    if (g == 0) {
#pragma unroll
        for (int y = 0; y < 4; ++y) {
            u16 tmp[8];
#pragma unroll
            for (int j = 0; j < 8; ++j) tmp[j] = f2bf(acc[y][j]);
            *(bf16x8*)(Y + (size_t)(r0 + y) * FEAT + f * 8) = *(const bf16x8*)tmp;
        }
    }
}

// ------- streaming GEMM v2 (proven best): LDS-staged 32-row A tile,
//         fragment-packed Wp2, K=384 over 3 planes.

template <int O, bool RELU, bool RES, bool OUT_F32>
__global__ __launch_bounds__(256) void gemm_kernel(const u16* __restrict__ H,
                                                   const u16* __restrict__ T1,
                                                   const u16* __restrict__ S2,
                                                   const u16* __restrict__ Wp2,
                                                   const float* __restrict__ bias,
                                                   void* __restrict__ outv) {
    __shared__ __align__(16) u16 sA[3][32][LDS_PITCH];    // 25.5 KB
    int tid = threadIdx.x;
    int m0 = blockIdx.x * 32;                             // N_NODES % 32 == 0

#pragma unroll
    for (int p = 0; p < 3; ++p) {
        const u16* sp = (p == 0) ? H : (p == 1) ? T1 : S2;
#pragma unroll
        for (int u = 0; u < 2; ++u) {
            int unit = u * 256 + tid;
            int row = unit >> 4, seg = unit & 15;
            *(bf16x8*)&sA[p][row][seg * 8] =
                *(const bf16x8*)(sp + (size_t)(m0 + row) * FEAT + seg * 8);
        }
    }
    __syncthreads();

    int lane = tid & 63, wid = tid >> 6;
    int r = lane & 15, q = lane >> 4;
    constexpr int NW = O / 64;          // 2 for O=128, 1 for O=64
    f32x4 acc0[NW], acc1[NW];
#pragma unroll
    for (int t = 0; t < NW; ++t) {
        acc0[t] = (f32x4){0.f, 0.f, 0.f, 0.f};
        acc1[t] = (f32x4){0.f, 0.f, 0.f, 0.f};
    }

#pragma unroll
    for (int kk = 0; kk < 12; ++kk) {
        int p = kk >> 2, ko = kk & 3;
        bf16x8 af0 = *(const bf16x8*)&sA[p][r][ko * 32 + q * 8];
        bf16x8 af1 = *(const bf16x8*)&sA[p][16 + r][ko * 32 + q * 8];
#pragma unroll
        for (int t = 0; t < NW; ++t) {
            int ot = wid * NW + t;
            bf16x8 bfr = *(const bf16x8*)(Wp2 + ((size_t)(ot * 12 + kk) * 64 + lane) * 8);
            acc0[t] = __builtin_amdgcn_mfma_f32_16x16x32_bf16(af0, bfr, acc0[t], 0, 0, 0);
            acc1[t] = __builtin_amdgcn_mfma_f32_16x16x32_bf16(af1, bfr, acc1[t], 0, 0, 0);
        }
    }

#pragma unroll
    for (int t = 0; t < NW; ++t) {
        int col = (wid * NW + t) * 16 + r;
        float bv = bias[col];
#pragma unroll
        for (int i = 0; i < 4; ++i) {
            int lrow = q * 4 + i;
            float v0 = acc0[t][i] + bv;
            if (RES)  v0 += bf2f(sA[0][lrow][col]);
            if (RELU) v0 = fmaxf(v0, 0.f);
            float v1 = acc1[t][i] + bv;
            if (RES)  v1 += bf2f(sA[0][16 + lrow][col]);
            if (RELU) v1 = fmaxf(v1, 0.f);
            if (OUT_F32) {
                ((float*)outv)[(size_t)(m0 + lrow) * O + col] = v0;
                ((float*)outv)[(size_t)(m0 + 16 + lrow) * O + col] = v1;
            } else {
                ((u16*)outv)[(size_t)(m0 + lrow) * O + col] = f2bf(v0);
                ((u16*)outv)[(size_t)(m0 + 16 + lrow) * O + col] = f2bf(v1);
            }
        }
    }
}

// ------- single-plane GEMM (K=128): out = X@P (+add) (+bias), layer-4 path

template <int O, bool OUT_F32, bool ADDT, bool BIAS>
__global__ __launch_bounds__(256) void gemm1p_kernel(const u16* __restrict__ X,
                                                     const u16* __restrict__ P,
                                                     const u16* __restrict__ addp,
                                                     const float* __restrict__ bias,
                                                     void* __restrict__ outv) {
    __shared__ __align__(16) u16 sA[32][LDS_PITCH];       // 8.5 KB
    int tid = threadIdx.x;
    int m0 = blockIdx.x * 32;

#pragma unroll
    for (int u = 0; u < 2; ++u) {
        int unit = u * 256 + tid;
        int row = unit >> 4, seg = unit & 15;
        *(bf16x8*)&sA[row][seg * 8] =
            *(const bf16x8*)(X + (size_t)(m0 + row) * FEAT + seg * 8);
    }
    __syncthreads();

    int lane = tid & 63, wid = tid >> 6;
    int r = lane & 15, q = lane >> 4;
    constexpr int NW = O / 64;
    f32x4 acc0[NW], acc1[NW];
#pragma unroll
    for (int t = 0; t < NW; ++t) {
        acc0[t] = (f32x4){0.f, 0.f, 0.f, 0.f};
        acc1[t] = (f32x4){0.f, 0.f, 0.f, 0.f};
    }

#pragma unroll
    for (int kk = 0; kk < 4; ++kk) {
        bf16x8 af0 = *(const bf16x8*)&sA[r][kk * 32 + q * 8];
        bf16x8 af1 = *(const bf16x8*)&sA[16 + r][kk * 32 + q * 8];
#pragma unroll
        for (int t = 0; t < NW; ++t) {
            int ot = wid * NW + t;
            bf16x8 bfr = *(const bf16x8*)(P + ((size_t)(ot * 4 + kk) * 64 + lane) * 8);
            acc0[t] = __builtin_amdgcn_mfma_f32_16x16x32_bf16(af0, bfr, acc0[t], 0, 0, 0);
            acc1[t] = __builtin_amdgcn_mfma_f32_16x16x32_bf16(af1, bfr, acc1[t], 0, 0, 0);
        }
    }

#pragma unroll
    for (int t = 0; t < NW; ++t) {
        int col = (wid * NW + t) * 16 + r;
        float bv = BIAS ? bias[col] : 0.f;
#pragma unroll
        for (int i = 0; i < 4; ++i) {
            int lrow = q * 4 + i;
            int row0 = m0 + lrow, row1 = m0 + 16 + lrow;
            float v0 = acc0[t][i] + bv;
            float v1 = acc1[t][i] + bv;
            if (ADDT) {
                v0 += bf2f(addp[(size_t)row0 * O + col]);
                v1 += bf2f(addp[(size_t)row1 * O + col]);
            }
            if (OUT_F32) {
                ((float*)outv)[(size_t)row0 * O + col] = v0;
                ((float*)outv)[(size_t)row1 * O + col] = v1;
            } else {
                ((u16*)outv)[(size_t)row0 * O + col] = f2bf(v0);
                ((u16*)outv)[(size_t)row1 * O + col] = f2bf(v1);
            }
        }
    }
}

// ------- fallback fused kernel (ws too small for split path) ---------------

template <int O, bool RELU, bool RES, bool OUT_F32>
__global__ __launch_bounds__(256) void fused_gemm_kernel(const int* __restrict__ row_ptr,
                                                         const int2* __restrict__ ecw,
                                                         const u16* __restrict__ H,
                                                         const u16* __restrict__ T1,
                                                         const u16* __restrict__ Wp,
                                                         const float* __restrict__ bias,
                                                         void* __restrict__ outv) {
    __shared__ __align__(16) u16 sT[16 * LDS_PITCH];
    int wid = threadIdx.x >> 6;
    int lane = threadIdx.x & 63;
    int g = lane >> 4, f = lane & 15;
    int m0 = blockIdx.x * 16;

    {
        float acc[4][8];
        gather4(row_ptr, ecw, T1, m0 + wid * 4, lane, g, f, acc);
        if (g == 0) {
#pragma unroll
            for (int y = 0; y < 4; ++y) {
                u16 tmp[8];
#pragma unroll
                for (int j = 0; j < 8; ++j) tmp[j] = f2bf(acc[y][j]);
                *(bf16x8*)(sT + (wid * 4 + y) * LDS_PITCH + f * 8) = *(const bf16x8*)tmp;
            }
        }
    }
    __syncthreads();

    int r = f, q = g;
    constexpr int NT = O / 16;
    constexpr int NW = NT / 4;
    f32x4 acc[NW];
#pragma unroll
    for (int t = 0; t < NW; ++t) acc[t] = (f32x4){0.f, 0.f, 0.f, 0.f};

#pragma unroll
    for (int kk = 0; kk < 12; ++kk) {
        bf16x8 af;
        if (kk < 4)
            af = *(const bf16x8*)(H + (size_t)(m0 + r) * FEAT + kk * 32 + q * 8);
        else if (kk < 8)
            af = *(const bf16x8*)(T1 + (size_t)(m0 + r) * FEAT + (kk - 4) * 32 + q * 8);
        else
            af = *(const bf16x8*)(sT + r * LDS_PITCH + (kk - 8) * 32 + q * 8);
#pragma unroll
        for (int t = 0; t < NW; ++t) {
            int ot = wid * NW + t;
            bf16x8 bfr = *(const bf16x8*)(Wp + (size_t)(ot * 16 + r) * 384 + kk * 32 + q * 8);
            acc[t] = __builtin_amdgcn_mfma_f32_16x16x32_bf16(af, bfr, acc[t], 0, 0, 0);
        }
    }

#pragma unroll
    for (int t = 0; t < NW; ++t) {
        int col = (wid * NW + t) * 16 + r;
        float bv = bias[col];
#pragma unroll
        for (int i = 0; i < 4; ++i) {
            int row = m0 + q * 4 + i;
            float v = acc[t][i] + bv;
            if (RES)  v += bf2f(H[(size_t)row * FEAT + col]);
            if (RELU) v = fmaxf(v, 0.f);
            if (OUT_F32) ((float*)outv)[(size_t)row * O + col] = v;
            else         ((u16*)outv)[(size_t)row * O + col] = f2bf(v);
        }
    }
}

// ---------------- launcher ----------------

static inline size_t align_up(size_t x) { return (x + 255) & ~(size_t)255; }

extern "C" void kernel_launch(void* const* d_in, const int* in_sizes, int n_in,
                              void* d_out, int out_size, void* d_ws, size_t ws_size,
                              hipStream_t stream) {
    const float* x     = (const float*)d_in[0];
    const int*   ei    = (const int*)d_in[1];
    const float* ew    = (const float*)d_in[2];
    const float* W_in  = (const float*)d_in[3];
    const float* b_in  = (const float*)d_in[4];
    const float* W_h1  = (const float*)d_in[5];
    const float* b_h1  = (const float*)d_in[6];
    const float* W_h2  = (const float*)d_in[7];
    const float* b_h2  = (const float*)d_in[8];
    const float* W_out = (const float*)d_in[9];
    const float* b_out = (const float*)d_in[10];

    const int* rows = ei;
    const int* cols = ei + N_EDGES;

    // workspace layout
    char* w = (char*)d_ws;
    size_t off = 0;
    int* counts = (int*)(w + off);            off = align_up(off + (size_t)N_NODES * 4);   // fallback fill
    int* row_ptr= (int*)(w + off);            off = align_up(off + (size_t)(N_NODES + 1) * 4);
    int* bsum   = (int*)(w + off);            off = align_up(off + 512 * 4);               // NBKT+1 fits
    int2* ecw   = (int2*)(w + off);           off = align_up(off + (size_t)N_EDGES * 8);
    u16* t1     = (u16*)(w + off);            off = align_up(off + (size_t)N_NODES * FEAT * 2);
    u16* h      = (u16*)(w + off);            off = align_up(off + (size_t)N_NODES * FEAT * 2);
    u16* Wp_in  = (u16*)(w + off);            off = align_up(off + (size_t)128 * 384 * 2);
    u16* Wp_h1  = (u16*)(w + off);            off = align_up(off + (size_t)128 * 384 * 2);
    u16* Wp_h2  = (u16*)(w + off);            off = align_up(off + (size_t)128 * 384 * 2);
    u16* Wp_out = (u16*)(w + off);            off = align_up(off + (size_t)64 * 384 * 2);
    // split path: s2 buffer (doubles as ebuf during CSR build), fragment-packed
    // weights (3 hidden K=384 + layer-4 K=128 pair), deterministic CSR counters
    u16* s2     = (u16*)(w + off);            size_t off2 = align_up(off + (size_t)N_NODES * FEAT * 2);
    u16* W2_in  = (u16*)(w + off2);           off2 = align_up(off2 + (size_t)128 * 384 * 2);
    u16* W2_h1  = (u16*)(w + off2);           off2 = align_up(off2 + (size_t)128 * 384 * 2);
    u16* W2_h2  = (u16*)(w + off2);           off2 = align_up(off2 + (size_t)128 * 384 * 2);
    u16* P_ab   = (u16*)(w + off2);           off2 = align_up(off2 + (size_t)2048 * 8 * 2);
    u16* P_f    = (u16*)(w + off2);           off2 = align_up(off2 + (size_t)1024 * 8 * 2);
    int* pcnt   = (int*)(w + off2);           off2 = align_up(off2 + (size_t)NBLK * NBKT * 4);
    int* gtot   = (int*)(w + off2);           off2 = align_up(off2 + (size_t)NBKT * 4);
    const bool use_split = (ws_size >= off2);
    static_assert((size_t)N_EDGES * 8 <= (size_t)N_NODES * FEAT * 2, "ebuf exceeds s2");

    cvt_kernel<<<(N_NODES * FEAT / 4 + 255) / 256, 256, 0, stream>>>(x, h);

    const int grid16 = N_NODES / 16;         // 6250 blocks (fallback)
    const int grid32 = N_NODES / 32;         // 3125 blocks: 32-row gemm tiles
    const int grid1  = N_NODES * 64 / 256;   // 25000 blocks: 1 row per wave

    if (use_split) {
        // CSR build v4: deterministic, zero global atomics, write-merged
        int2* ebuf = (int2*)s2;
        csr_passA_kernel<<<NBLK, 256, 0, stream>>>(rows, pcnt);
        csr_scanP_kernel<<<NBKT, 256, 0, stream>>>(pcnt, gtot);
        csr_scanG_kernel<<<1, 512, 0, stream>>>(gtot, bsum, row_ptr);
        csr_passB_kernel<<<NBLK, 256, 0, stream>>>(rows, cols, ew, pcnt, bsum, ebuf);
        csr_finalize_kernel<<<NBKT, 256, 0, stream>>>(bsum, ebuf, row_ptr, ecw);

        prep_w2_all_kernel<<<(18432 + 255) / 256, 256, 0, stream>>>(
            W_in, W_h1, W_h2, W2_in, W2_h1, W2_h2);
        prep_w4_kernel<<<(3072 + 255) / 256, 256, 0, stream>>>(W_out, P_ab, P_f);

        // Layers 1-3: unchanged proven path
        spmm1_kernel<<<grid1, 256, 0, stream>>>(row_ptr, ecw, h, t1);
        spmm1_kernel<<<grid1, 256, 0, stream>>>(row_ptr, ecw, t1, s2);
        gemm_kernel<128, true, false, false><<<grid32, 256, 0, stream>>>(h, t1, s2, W2_in, b_in, h);

        spmm1_kernel<<<grid1, 256, 0, stream>>>(row_ptr, ecw, h, t1);
        spmm1_kernel<<<grid1, 256, 0, stream>>>(row_ptr, ecw, t1, s2);
        gemm_kernel<128, true, true, false><<<grid32, 256, 0, stream>>>(h, t1, s2, W2_h1, b_h1, h);

        spmm1_kernel<<<grid1, 256, 0, stream>>>(row_ptr, ecw, h, t1);
        spmm1_kernel<<<grid1, 256, 0, stream>>>(row_ptr, ecw, t1, s2);
        gemm_kernel<128, true, true, false><<<grid32, 256, 0, stream>>>(h, t1, s2, W2_h2, b_h2, h);

        // Layer 4 (O=64) via associativity: gathers run 64-wide (1 line/edge)
        //   ab = h @ [W1o | 2*W2o]           (N x 128, bf16, into t1)
        //   d  = ab[:,0:64] + S*ab[:,64:128] (N x 64, into s2)
        //   e  = S*d                         (N x 64, into s2 + N*64)
        //   out = h @ (W0o - W2o) + e + b    (f32)
        {
            u16* ab = t1;
            u16* dbuf = s2;
            u16* ev = s2 + (size_t)N_NODES * 64;
            gemm1p_kernel<128, false, false, false><<<grid32, 256, 0, stream>>>(
                h, P_ab, nullptr, nullptr, ab);
            spmm64_kernel<true><<<grid1, 256, 0, stream>>>(
                row_ptr, ecw, ab + 64, 128, ab, 128, dbuf, 64);
            spmm64_kernel<false><<<grid1, 256, 0, stream>>>(
                row_ptr, ecw, dbuf, 64, nullptr, 0, ev, 64);
            gemm1p_kernel<64, true, true, true><<<grid32, 256, 0, stream>>>(
                h, P_f, ev, b_out, d_out);
        }
    } else {
        // fallback: legacy CSR build + fused path
        hipMemsetAsync(counts, 0, (size_t)N_NODES * 4, stream);
        hist_kernel<<<N_EDGES / 256, 256, 0, stream>>>(rows, counts);
        reduce_counts_kernel<<<NB_SCAN, 256, 0, stream>>>(counts, bsum);
        scan_bsums_kernel<<<1, 512, 0, stream>>>(bsum, row_ptr);
        write_rowptr_kernel<<<NB_SCAN, 256, 0, stream>>>(counts, bsum, row_ptr);
        scatter_kernel<<<N_EDGES / 256, 256, 0, stream>>>(rows, cols, ew, row_ptr, counts, ecw);

        prep_w_kernel<<<(128 * 384 + 255) / 256, 256, 0, stream>>>(W_in, Wp_in, 128);
        prep_w_kernel<<<(128 * 384 + 255) / 256, 256, 0, stream>>>(W_h1, Wp_h1, 128);
        prep_w_kernel<<<(128 * 384 + 255) / 256, 256, 0, stream>>>(W_h2, Wp_h2, 128);
        prep_w_kernel<<<(64 * 384 + 255) / 256, 256, 0, stream>>>(W_out, Wp_out, 64);

        spmm_kernel<<<grid16, 256, 0, stream>>>(row_ptr, ecw, h, t1);
        fused_gemm_kernel<128, true, false, false><<<grid16, 256, 0, stream>>>(
            row_ptr, ecw, h, t1, Wp_in, b_in, h);
        spmm_kernel<<<grid16, 256, 0, stream>>>(row_ptr, ecw, h, t1);
        fused_gemm_kernel<128, true, true, false><<<grid16, 256, 0, stream>>>(
            row_ptr, ecw, h, t1, Wp_h1, b_h1, h);
        spmm_kernel<<<grid16, 256, 0, stream>>>(row_ptr, ecw, h, t1);
        fused_gemm_kernel<128, true, true, false><<<grid16, 256, 0, stream>>>(
            row_ptr, ecw, h, t1, Wp_h2, b_h2, h);
        spmm_kernel<<<grid16, 256, 0, stream>>>(row_ptr, ecw, h, t1);
        fused_gemm_kernel<64, false, false, true><<<grid16, 256, 0, stream>>>(
            row_ptr, ecw, h, t1, Wp_out, b_out, d_out);
    }
}

// Round 13
// 667.534 us; speedup vs baseline: 1.1801x; 1.0128x over previous
//
#include <hip/hip_runtime.h>
#include <hip/hip_bf16.h>
#include <stdint.h>
#include <stddef.h>

#define N_NODES 100000
#define N_EDGES 1600000
#define FEAT 128
#define NB_SCAN ((N_NODES + 255) / 256)   // 391 blocks of 256 for the scan
#define LDS_PITCH 136                     // u16; 272 B/row: uniform bank spread for b128
#define CAP 24                            // edges per gather chunk
#define NL (CAP / 4)                      // 6 load instructions per chunk (128-wide gather)
#define NL64 (CAP / 8)                    // 3 load instructions per chunk (64-wide gather)
#define NBKT ((N_NODES + 255) / 256)      // 391 row-buckets of 256 rows
#define EPB 2048                          // edges per CSR block
#define NBLK ((N_EDGES + EPB - 1) / EPB)  // 782 CSR blocks
#define EPT (EPB / 256)                   // 8 edges per thread

typedef __attribute__((ext_vector_type(8))) short bf16x8;
typedef __attribute__((ext_vector_type(4))) float f32x4;
typedef unsigned short u16;

__device__ __forceinline__ float bf2f(u16 u) {
    union { unsigned int i; float f; } v; v.i = ((unsigned int)u) << 16; return v.f;
}
__device__ __forceinline__ u16 f2bf(float f) {
    union { float f; unsigned int i; } v; v.f = f;
    unsigned int x = v.i;
    return (u16)((x + 0x7fffu + ((x >> 16) & 1u)) >> 16);   // round-nearest-even
}

// ---------------- CSR build: legacy kernels (fallback path) ----------------

__global__ void hist_kernel(const int* __restrict__ rows, int* __restrict__ counts) {
    int e = blockIdx.x * blockDim.x + threadIdx.x;
    if (e < N_EDGES) {
        int r = rows[e];
        r = min(max(r, 0), N_NODES - 1);
        atomicAdd(&counts[r], 1);
    }
}

__global__ void reduce_counts_kernel(const int* __restrict__ counts, int* __restrict__ bsum) {
    __shared__ int s[256];
    int i = blockIdx.x * 256 + threadIdx.x;
    int v = (i < N_NODES) ? counts[i] : 0;
    s[threadIdx.x] = v; __syncthreads();
    for (int off = 128; off > 0; off >>= 1) {
        if (threadIdx.x < off) s[threadIdx.x] += s[threadIdx.x + off];
        __syncthreads();
    }
    if (threadIdx.x == 0) bsum[blockIdx.x] = s[0];
}

__global__ void scan_bsums_kernel(int* __restrict__ bsum, int* __restrict__ row_ptr) {
    __shared__ int s[512];
    int t = threadIdx.x;
    int v = (t < NB_SCAN) ? bsum[t] : 0;
    s[t] = v; __syncthreads();
    for (int off = 1; off < 512; off <<= 1) {
        int x = (t >= off) ? s[t - off] : 0;
        __syncthreads();
        s[t] += x;
        __syncthreads();
    }
    if (t < NB_SCAN) bsum[t] = s[t] - v;              // exclusive
    if (t == NB_SCAN - 1) row_ptr[N_NODES] = s[t];    // total (= N_EDGES)
}

// also zeroes counts so it can be reused as the scatter fill array
__global__ void write_rowptr_kernel(int* __restrict__ counts, const int* __restrict__ bsum,
                                    int* __restrict__ row_ptr) {
    __shared__ int s[256];
    int i = blockIdx.x * 256 + threadIdx.x;
    int v = (i < N_NODES) ? counts[i] : 0;
    s[threadIdx.x] = v; __syncthreads();
    for (int off = 1; off < 256; off <<= 1) {
        int x = (threadIdx.x >= off) ? s[threadIdx.x - off] : 0;
        __syncthreads();
        s[threadIdx.x] += x;
        __syncthreads();
    }
    if (i < N_NODES) {
        row_ptr[i] = bsum[blockIdx.x] + s[threadIdx.x] - v;  // exclusive
        counts[i] = 0;                                       // becomes fill[]
    }
}

// legacy random scatter (fallback path only)
__global__ void scatter_kernel(const int* __restrict__ rows, const int* __restrict__ cols,
                               const float* __restrict__ w, const int* __restrict__ row_ptr,
                               int* __restrict__ fill, int2* __restrict__ ecw) {
    int e = blockIdx.x * blockDim.x + threadIdx.x;
    if (e < N_EDGES) {
        int r = rows[e];
        r = min(max(r, 0), N_NODES - 1);
        int pos = row_ptr[r] + atomicAdd(&fill[r], 1);
        pos = min(max(pos, 0), N_EDGES - 1);
        int c = cols[e];
        c = min(max(c, 0), N_NODES - 1);
        ecw[pos] = make_int2(c, __float_as_int(w[e]));
    }
}

// ---------------- CSR build v4: deterministic, zero global atomics ---------

__global__ __launch_bounds__(256) void csr_passA_kernel(const int* __restrict__ rows,
                                                        int* __restrict__ pcnt) {
    __shared__ int s_cnt[NBKT];
    int tid = threadIdx.x, blk = blockIdx.x;
    for (int b = tid; b < NBKT; b += 256) s_cnt[b] = 0;
    __syncthreads();
    int e0 = blk * EPB;
#pragma unroll
    for (int it = 0; it < EPT; ++it) {
        int e = e0 + it * 256 + tid;
        if (e < N_EDGES) {
            int r = min(max(rows[e], 0), N_NODES - 1);
            atomicAdd(&s_cnt[r >> 8], 1);
        }
    }
    __syncthreads();
    for (int b = tid; b < NBKT; b += 256)
        pcnt[(size_t)blk * NBKT + b] = s_cnt[b];      // coalesced 1.5 KB store
}

__global__ __launch_bounds__(256) void csr_scanP_kernel(int* __restrict__ pcnt,
                                                        int* __restrict__ gtot) {
    __shared__ int s[256];
    int b = blockIdx.x, tid = threadIdx.x;
    int carry = 0;
    for (int c = 0; c < (NBLK + 255) / 256; ++c) {
        int idx = c * 256 + tid;
        int v = (idx < NBLK) ? pcnt[(size_t)idx * NBKT + b] : 0;
        s[tid] = v; __syncthreads();
        for (int off = 1; off < 256; off <<= 1) {
            int x = (tid >= off) ? s[tid - off] : 0;
            __syncthreads();
            s[tid] += x;
            __syncthreads();
        }
        if (idx < NBLK) pcnt[(size_t)idx * NBKT + b] = carry + s[tid] - v;  // exclusive
        carry += s[255];
        __syncthreads();
    }
    if (tid == 0) gtot[b] = carry;
}

__global__ void csr_scanG_kernel(const int* __restrict__ gtot, int* __restrict__ bsum,
                                 int* __restrict__ row_ptr) {
    __shared__ int s[512];
    int t = threadIdx.x;
    int v = (t < NBKT) ? gtot[t] : 0;
    s[t] = v; __syncthreads();
    for (int off = 1; off < 512; off <<= 1) {
        int x = (t >= off) ? s[t - off] : 0;
        __syncthreads();
        s[t] += x;
        __syncthreads();
    }
    if (t < NBKT) bsum[t] = s[t] - v;                 // exclusive bucket base
    if (t == NBKT - 1) {
        bsum[NBKT] = s[t];                            // total
        row_ptr[N_NODES] = s[t];
    }
}

__global__ __launch_bounds__(256) void csr_passB_kernel(const int* __restrict__ rows,
                                                        const int* __restrict__ cols,
                                                        const float* __restrict__ w,
                                                        const int* __restrict__ pcnt,
                                                        const int* __restrict__ bsum,
                                                        int2* __restrict__ ebuf) {
    __shared__ int s_base[NBKT];      // global dest base per bucket for this block
    __shared__ int s_cnt[NBKT];       // hist, then fill
    __shared__ int s_off[NBKT];       // exclusive offsets in sorted LDS array
    __shared__ int s_scan[512];
    __shared__ int2 s_sorted[EPB];    // 16 KB payload sorted by bucket
    __shared__ int s_dst[EPB];        // 8 KB destination slots
    int tid = threadIdx.x, blk = blockIdx.x;
    for (int b = tid; b < NBKT; b += 256) {
        s_base[b] = bsum[b] + pcnt[(size_t)blk * NBKT + b];
        s_cnt[b] = 0;
    }
    __syncthreads();
    int e0 = blk * EPB;
    int n = min(N_EDGES - e0, EPB);

    int2 pay[EPT]; int pb[EPT];
#pragma unroll
    for (int it = 0; it < EPT; ++it) {
        int e = e0 + it * 256 + tid;
        if (e < N_EDGES) {
            int r = min(max(rows[e], 0), N_NODES - 1);
            int c = min(max(cols[e], 0), N_NODES - 1);
            pay[it] = make_int2(c | ((r & 255) << 20), __float_as_int(w[e]));
            pb[it] = r >> 8;
            atomicAdd(&s_cnt[pb[it]], 1);
        } else {
            pb[it] = -1;
        }
    }
    __syncthreads();
    s_scan[tid] = (tid < NBKT) ? s_cnt[tid] : 0;
    s_scan[tid + 256] = (tid + 256 < NBKT) ? s_cnt[tid + 256] : 0;
    __syncthreads();
    for (int off = 1; off < 512; off <<= 1) {
        int a = (tid >= off) ? s_scan[tid - off] : 0;
        int b2 = (tid + 256 >= off) ? s_scan[tid + 256 - off] : 0;
        __syncthreads();
        s_scan[tid] += a;
        s_scan[tid + 256] += b2;
        __syncthreads();
    }
    for (int b = tid; b < NBKT; b += 256) {
        s_off[b] = s_scan[b] - s_cnt[b];
        s_cnt[b] = 0;                                  // becomes fill counter
    }
    __syncthreads();
#pragma unroll
    for (int it = 0; it < EPT; ++it) {
        if (pb[it] >= 0) {
            int k = atomicAdd(&s_cnt[pb[it]], 1);
            int slot = s_off[pb[it]] + k;
            s_sorted[slot] = pay[it];
            s_dst[slot] = s_base[pb[it]] + k;
        }
    }
    __syncthreads();
    for (int p = tid; p < n; p += 256)
        ebuf[s_dst[p]] = s_sorted[p];
}

__global__ __launch_bounds__(256) void csr_finalize_kernel(const int* __restrict__ bsum,
                                                           const int2* __restrict__ ebuf,
                                                           int* __restrict__ row_ptr,
                                                           int2* __restrict__ ecw) {
    __shared__ int s_cnt[256];
    __shared__ int s_pos[256];
    int b = blockIdx.x, tid = threadIdx.x;
    int base = bsum[b];
    int cnt = bsum[b + 1] - base;
    s_cnt[tid] = 0; __syncthreads();
    for (int i = tid; i < cnt; i += 256)
        atomicAdd(&s_cnt[ebuf[base + i].x >> 20], 1);
    __syncthreads();
    int v = s_cnt[tid];
    s_pos[tid] = v; __syncthreads();
    for (int off = 1; off < 256; off <<= 1) {
        int x = (tid >= off) ? s_pos[tid - off] : 0;
        __syncthreads();
        s_pos[tid] += x;
        __syncthreads();
    }
    int excl = s_pos[tid] - v;
    int r = b * 256 + tid;
    if (r < N_NODES) row_ptr[r] = base + excl;
    s_cnt[tid] = excl;                                 // running fill
    __syncthreads();
    for (int i = tid; i < cnt; i += 256) {
        int2 p = ebuf[base + i];
        int rl = p.x >> 20;
        int pos = base + atomicAdd(&s_cnt[rl], 1);
        pos = min(max(pos, 0), N_EDGES - 1);
        ecw[pos] = make_int2(p.x & 0xFFFFF, p.y);
    }
}

// -------- weight prep ------------------------------------------------------
__device__ __forceinline__ float w_fold(const float* W, int o, int k) {
    if (k < 128)      return W[o * 384 + k] - W[o * 384 + 256 + k];
    else if (k < 256) return W[o * 384 + k];
    else              return 2.0f * W[o * 384 + k];
}

__global__ void prep_w_kernel(const float* __restrict__ W, u16* __restrict__ Wp, int O) {
    int i = blockIdx.x * blockDim.x + threadIdx.x;
    if (i >= O * 384) return;
    int o = i / 384, k = i % 384;
    Wp[i] = f2bf(w_fold(W, o, k));
}

// MFMA-fragment-packed W' (K=384) for the 3 hidden layers, one launch.
__global__ void prep_w2_all_kernel(const float* __restrict__ Wa, const float* __restrict__ Wb,
                                   const float* __restrict__ Wc,
                                   u16* __restrict__ Pa, u16* __restrict__ Pb,
                                   u16* __restrict__ Pc) {
    int i = blockIdx.x * blockDim.x + threadIdx.x;   // 3*6144 = 18432 units
    const float* W; u16* P; int il;
    if (i < 6144)       { W = Wa; P = Pa; il = i; }
    else if (i < 12288) { W = Wb; P = Pb; il = i - 6144; }
    else if (i < 18432) { W = Wc; P = Pc; il = i - 12288; }
    else return;
    int ot = il / 768;
    int rem = il % 768;
    int kk = rem / 64;
    int l = rem % 64;
    int q = l >> 4, r = l & 15;
    int o = ot * 16 + r;
    int kbase = kk * 32 + q * 8;
#pragma unroll
    for (int j = 0; j < 8; ++j)
        P[(size_t)il * 8 + j] = f2bf(w_fold(W, o, kbase + j));
}

// Layer-4 associativity weights (K=128 fragpack, unit = (ot*4+kk)*64+lane):
//   Pab (O=128): cols 0..63 = W_out[o][128+k]  (W1 term -> 'a')
//                cols 64..127 = 2*W_out[o-64][256+k]  (2*W2 term -> 'b')
//   Pf  (O=64):  W_out[o][k] - W_out[o][256+k]  (W0 - W2 term)
__global__ void prep_w4_kernel(const float* __restrict__ Wo,
                               u16* __restrict__ Pab, u16* __restrict__ Pf) {
    int i = blockIdx.x * blockDim.x + threadIdx.x;   // 2048 + 1024 = 3072 units
    if (i >= 3072) return;
    u16* P; int il; bool is_ab;
    if (i < 2048) { P = Pab; il = i; is_ab = true; }
    else          { P = Pf;  il = i - 2048; is_ab = false; }
    int ot = il / 256;           // 4 kk * 64 lanes
    int rem = il % 256;
    int kk = rem / 64;
    int l = rem % 64;
    int q = l >> 4, r = l & 15;
    int o = ot * 16 + r;
    int kbase = kk * 32 + q * 8;
#pragma unroll
    for (int j = 0; j < 8; ++j) {
        int k = kbase + j;
        float v;
        if (is_ab) {
            if (o < 64) v = Wo[o * 384 + 128 + k];
            else        v = 2.0f * Wo[(o - 64) * 384 + 256 + k];
        } else {
            v = Wo[o * 384 + k] - Wo[o * 384 + 256 + k];
        }
        P[(size_t)il * 8 + j] = f2bf(v);
    }
}

// -------- x (f32) -> bf16, 4 elems per thread ----------

__global__ void cvt_kernel(const float* __restrict__ x, u16* __restrict__ y) {
    int i = blockIdx.x * blockDim.x + threadIdx.x;
    if (i >= N_NODES * FEAT / 4) return;
    float4 v = ((const float4*)x)[i];
    ushort4 o;
    o.x = f2bf(v.x); o.y = f2bf(v.y); o.z = f2bf(v.z); o.w = f2bf(v.w);
    ((ushort4*)y)[i] = o;
}

// -------- branch-free register gather primitives --------------------------

__device__ __forceinline__ void load_meta(const int2* __restrict__ ecw, int s, int n,
                                          int lane, int& call, float& wall) {
    int idx = s + max(0, min(lane, n - 1));       // clamp: branch-free
    idx = min(idx, N_EDGES - 1);                  // deg-0 last-row guard
    int2 cw = ecw[idx];
    call = cw.x;
    wall = (lane < n) ? __int_as_float(cw.y) : 0.f;   // cndmask, no branch
}

__device__ __forceinline__ void issue_row(const u16* __restrict__ X, int call,
                                          int g, int f, bf16x8* q) {
#pragma unroll
    for (int k = 0; k < NL; ++k) {
        int col = __shfl(call, k * 4 + g);
        q[k] = *(const bf16x8*)(X + (size_t)col * FEAT + f * 8);
    }
}

__device__ __forceinline__ void reduce_row(const bf16x8* q, float wall,
                                           int g, float* acc) {
#pragma unroll
    for (int k = 0; k < NL; ++k) {
        float wj = __shfl(wall, k * 4 + g);
#pragma unroll
        for (int j = 0; j < 8; ++j) acc[j] += wj * bf2f((u16)q[k][j]);
    }
}

// -------- SpMM v3 (proven best): ONE ROW PER WAVE, 128-wide table ---------

__global__ __launch_bounds__(256) void spmm1_kernel(const int* __restrict__ row_ptr,
                                                    const int2* __restrict__ ecw,
                                                    const u16* __restrict__ X,
                                                    u16* __restrict__ Y) {
    int lane = threadIdx.x & 63;
    int g = lane >> 4, f = lane & 15;
    int rr = (blockIdx.x * blockDim.x + threadIdx.x) >> 6;   // 1 row per wave

    int s = row_ptr[rr], e = row_ptr[rr + 1];
    float acc[8];
#pragma unroll
    for (int j = 0; j < 8; ++j) acc[j] = 0.f;

    {   // main chunk (covers 98% of Poisson-16 rows entirely)
        int call; float wall;
        load_meta(ecw, s, min(e - s, CAP), lane, call, wall);
        bf16x8 q[NL];
        issue_row(X, call, g, f, q);
        reduce_row(q, wall, g, acc);
    }
    for (int cs = s + CAP; cs < e; cs += CAP) {   // rare tail (deg > 24)
        int c2; float w2;
        load_meta(ecw, cs, min(e - cs, CAP), lane, c2, w2);
        bf16x8 qt[NL];
        issue_row(X, c2, g, f, qt);
        reduce_row(qt, w2, g, acc);
    }

#pragma unroll
    for (int j = 0; j < 8; ++j) {
        acc[j] += __shfl_xor(acc[j], 16);
        acc[j] += __shfl_xor(acc[j], 32);
    }
    if (g == 0) {
        u16 tmp[8];
#pragma unroll
        for (int j = 0; j < 8; ++j) tmp[j] = f2bf(acc[j]);
        *(bf16x8*)(Y + (size_t)rr * FEAT + f * 8) = *(const bf16x8*)tmp;
    }
}

// -------- SpMM64: one row/wave over a 64-wide bf16 table (1 line/edge) ----

template <bool ADDT>
__global__ __launch_bounds__(256) void spmm64_kernel(const int* __restrict__ row_ptr,
                                                     const int2* __restrict__ ecw,
                                                     const u16* __restrict__ X, int ldx,
                                                     const u16* __restrict__ A, int lda,
                                                     u16* __restrict__ Y, int ldy) {
    int lane = threadIdx.x & 63;
    int g = lane >> 3, f = lane & 7;
    int rr = (blockIdx.x * blockDim.x + threadIdx.x) >> 6;   // 1 row per wave

    int s = row_ptr[rr], e = row_ptr[rr + 1];
    float acc[8];
#pragma unroll
    for (int j = 0; j < 8; ++j) acc[j] = 0.f;

    {
        int call; float wall;
        load_meta(ecw, s, min(e - s, CAP), lane, call, wall);
        bf16x8 q[NL64];
#pragma unroll
        for (int k = 0; k < NL64; ++k) {
            int col = __shfl(call, k * 8 + g);
            q[k] = *(const bf16x8*)(X + (size_t)col * ldx + f * 8);
        }
#pragma unroll
        for (int k = 0; k < NL64; ++k) {
            float wj = __shfl(wall, k * 8 + g);
#pragma unroll
            for (int j = 0; j < 8; ++j) acc[j] += wj * bf2f((u16)q[k][j]);
        }
    }
    for (int cs = s + CAP; cs < e; cs += CAP) {   // rare tail (deg > 24)
        int c2; float w2;
        load_meta(ecw, cs, min(e - cs, CAP), lane, c2, w2);
        bf16x8 qt[NL64];
#pragma unroll
        for (int k = 0; k < NL64; ++k) {
            int col = __shfl(c2, k * 8 + g);
            qt[k] = *(const bf16x8*)(X + (size_t)col * ldx + f * 8);
        }
#pragma unroll
        for (int k = 0; k < NL64; ++k) {
            float wj = __shfl(w2, k * 8 + g);
#pragma unroll
            for (int j = 0; j < 8; ++j) acc[j] += wj * bf2f((u16)qt[k][j]);
        }
    }

#pragma unroll
    for (int j = 0; j < 8; ++j) {
        acc[j] += __shfl_xor(acc[j], 8);
        acc[j] += __shfl_xor(acc[j], 16);
        acc[j] += __shfl_xor(acc[j], 32);
    }
    if (g == 0) {
        if (ADDT) {
            bf16x8 av = *(const bf16x8*)(A + (size_t)rr * lda + f * 8);
#pragma unroll
            for (int j = 0; j < 8; ++j) acc[j] += bf2f((u16)av[j]);
        }
        u16 tmp[8];
#pragma unroll
        for (int j = 0; j < 8; ++j) tmp[j] = f2bf(acc[j]);
        *(bf16x8*)(Y + (size_t)rr * ldy + f * 8) = *(const bf16x8*)tmp;
    }
}

// -------- gather4 (fallback fused path only) ------------------------------

__device__ __forceinline__ void gather4(const int* __restrict__ row_ptr,
                                        const int2* __restrict__ ecw,
                                        const u16* __restrict__ X,
                                        int r0, int lane, int g, int f,
                                        float acc[4][8]) {
    int s[4], e[4];
    int call[4]; float wall[4];
#pragma unroll
    for (int y = 0; y < 4; ++y) {
        s[y] = row_ptr[r0 + y];
        e[y] = row_ptr[r0 + y + 1];
    }
#pragma unroll
    for (int y = 0; y < 4; ++y)
        load_meta(ecw, s[y], min(e[y] - s[y], CAP), lane, call[y], wall[y]);
#pragma unroll
    for (int y = 0; y < 4; ++y)
#pragma unroll
        for (int j = 0; j < 8; ++j) acc[y][j] = 0.f;

    bf16x8 q0[NL], q1[NL], q2[NL], q3[NL];
    issue_row(X, call[0], g, f, q0);
    issue_row(X, call[1], g, f, q1);
    reduce_row(q0, wall[0], g, acc[0]);
    issue_row(X, call[2], g, f, q2);
    reduce_row(q1, wall[1], g, acc[1]);
    issue_row(X, call[3], g, f, q3);
    reduce_row(q2, wall[2], g, acc[2]);
    reduce_row(q3, wall[3], g, acc[3]);

#pragma unroll
    for (int y = 0; y < 4; ++y) {
        for (int cs = s[y] + CAP; cs < e[y]; cs += CAP) {
            int c2; float w2;
            load_meta(ecw, cs, min(e[y] - cs, CAP), lane, c2, w2);
            bf16x8 qt[NL];
            issue_row(X, c2, g, f, qt);
            reduce_row(qt, w2, g, acc[y]);
        }
    }

#pragma unroll
    for (int y = 0; y < 4; ++y)
#pragma unroll
        for (int j = 0; j < 8; ++j) {
            acc[y][j] += __shfl_xor(acc[y][j], 16);
            acc[y][j] += __shfl_xor(acc[y][j], 32);
        }
}

// legacy 4-rows-per-wave spmm (fallback path)
__global__ __launch_bounds__(256) void spmm_kernel(const int* __restrict__ row_ptr,
                                                   const int2* __restrict__ ecw,
                                                   const u16* __restrict__ X,
                                                   u16* __restrict__ Y) {
    int wid = threadIdx.x >> 6;
    int lane = threadIdx.x & 63;
    int g = lane >> 4, f = lane & 15;
    int r0 = blockIdx.x * 16 + wid * 4;

    float acc[4][8];
    gather4(row_ptr, ecw, X, r0, lane, g, f, acc);

    if (g == 0) {
#pragma unroll
        for (int y = 0; y < 4; ++y) {
            u16 tmp[8];
#pragma unroll
            for (int j = 0; j < 8; ++j) tmp[j] = f2bf(acc[y][j]);
            *(bf16x8*)(Y + (size_t)(r0 + y) * FEAT + f * 8) = *(const bf16x8*)tmp;
        }
    }
}

// ------- streaming GEMM v4 (K=384, O=128): 8 waves, ONE column-tile per
//         wave -> all 12 B-fragments prefetched into registers (48 VGPR),
//         MFMA loop runs pure LDS+register with zero L2 dependency.

template <bool RELU, bool RES>
__global__ __launch_bounds__(512) void gemm8_kernel(const u16* __restrict__ H,
                                                    const u16* __restrict__ T1,
                                                    const u16* __restrict__ S2,
                                                    const u16* __restrict__ Wp2,
                                                    const float* __restrict__ bias,
                                                    u16* __restrict__ outp) {
    __shared__ __align__(16) u16 sA[3][32][LDS_PITCH];    // 25.5 KB
    int tid = threadIdx.x;
    int m0 = blockIdx.x * 32;                             // N_NODES % 32 == 0

    // stage 3 planes x 32 rows x 256B: 512 units of 16B per plane, 1 iter each
    {
        int row = tid >> 4, seg = tid & 15;
#pragma unroll
        for (int p = 0; p < 3; ++p) {
            const u16* sp = (p == 0) ? H : (p == 1) ? T1 : S2;
            *(bf16x8*)&sA[p][row][seg * 8] =
                *(const bf16x8*)(sp + (size_t)(m0 + row) * FEAT + seg * 8);
        }
    }

    int lane = tid & 63, wid = tid >> 6;                  // 8 waves, ot = wid
    int r = lane & 15, q = lane >> 4;

    // prefetch the wave's full B set while staging is in flight
    bf16x8 bfr[12];
#pragma unroll
    for (int kk = 0; kk < 12; ++kk)
        bfr[kk] = *(const bf16x8*)(Wp2 + ((size_t)(wid * 12 + kk) * 64 + lane) * 8);

    __syncthreads();

    f32x4 acc0 = (f32x4){0.f, 0.f, 0.f, 0.f};
    f32x4 acc1 = (f32x4){0.f, 0.f, 0.f, 0.f};
#pragma unroll
    for (int kk = 0; kk < 12; ++kk) {
        int p = kk >> 2, ko = kk & 3;
        bf16x8 af0 = *(const bf16x8*)&sA[p][r][ko * 32 + q * 8];
        bf16x8 af1 = *(const bf16x8*)&sA[p][16 + r][ko * 32 + q * 8];
        acc0 = __builtin_amdgcn_mfma_f32_16x16x32_bf16(af0, bfr[kk], acc0, 0, 0, 0);
        acc1 = __builtin_amdgcn_mfma_f32_16x16x32_bf16(af1, bfr[kk], acc1, 0, 0, 0);
    }

    int col = wid * 16 + r;
    float bv = bias[col];
#pragma unroll
    for (int i = 0; i < 4; ++i) {
        int lrow = q * 4 + i;
        float v0 = acc0[i] + bv;
        if (RES)  v0 += bf2f(sA[0][lrow][col]);
        if (RELU) v0 = fmaxf(v0, 0.f);
        float v1 = acc1[i] + bv;
        if (RES)  v1 += bf2f(sA[0][16 + lrow][col]);
        if (RELU) v1 = fmaxf(v1, 0.f);
        outp[(size_t)(m0 + lrow) * 128 + col] = f2bf(v0);
        outp[(size_t)(m0 + 16 + lrow) * 128 + col] = f2bf(v1);
    }
}

// ------- single-plane GEMM (K=128): out = X@P (+add) (+bias), layer-4 path

template <int O, bool OUT_F32, bool ADDT, bool BIAS>
__global__ __launch_bounds__(256) void gemm1p_kernel(const u16* __restrict__ X,
                                                     const u16* __restrict__ P,
                                                     const u16* __restrict__ addp,
                                                     const float* __restrict__ bias,
                                                     void* __restrict__ outv) {
    __shared__ __align__(16) u16 sA[32][LDS_PITCH];       // 8.5 KB
    int tid = threadIdx.x;
    int m0 = blockIdx.x * 32;

#pragma unroll
    for (int u = 0; u < 2; ++u) {
        int unit = u * 256 + tid;
        int row = unit >> 4, seg = unit & 15;
        *(bf16x8*)&sA[row][seg * 8] =
            *(const bf16x8*)(X + (size_t)(m0 + row) * FEAT + seg * 8);
    }
    __syncthreads();

    int lane = tid & 63, wid = tid >> 6;
    int r = lane & 15, q = lane >> 4;
    constexpr int NW = O / 64;
    f32x4 acc0[NW], acc1[NW];
#pragma unroll
    for (int t = 0; t < NW; ++t) {
        acc0[t] = (f32x4){0.f, 0.f, 0.f, 0.f};
        acc1[t] = (f32x4){0.f, 0.f, 0.f, 0.f};
    }

#pragma unroll
    for (int kk = 0; kk < 4; ++kk) {
        bf16x8 af0 = *(const bf16x8*)&sA[r][kk * 32 + q * 8];
        bf16x8 af1 = *(const bf16x8*)&sA[16 + r][kk * 32 + q * 8];
#pragma unroll
        for (int t = 0; t < NW; ++t) {
            int ot = wid * NW + t;
            bf16x8 bfr = *(const bf16x8*)(P + ((size_t)(ot * 4 + kk) * 64 + lane) * 8);
            acc0[t] = __builtin_amdgcn_mfma_f32_16x16x32_bf16(af0, bfr, acc0[t], 0, 0, 0);
            acc1[t] = __builtin_amdgcn_mfma_f32_16x16x32_bf16(af1, bfr, acc1[t], 0, 0, 0);
        }
    }

#pragma unroll
    for (int t = 0; t < NW; ++t) {
        int col = (wid * NW + t) * 16 + r;
        float bv = BIAS ? bias[col] : 0.f;
#pragma unroll
        for (int i = 0; i < 4; ++i) {
            int lrow = q * 4 + i;
            int row0 = m0 + lrow, row1 = m0 + 16 + lrow;
            float v0 = acc0[t][i] + bv;
            float v1 = acc1[t][i] + bv;
            if (ADDT) {
                v0 += bf2f(addp[(size_t)row0 * O + col]);
                v1 += bf2f(addp[(size_t)row1 * O + col]);
            }
            if (OUT_F32) {
                ((float*)outv)[(size_t)row0 * O + col] = v0;
                ((float*)outv)[(size_t)row1 * O + col] = v1;
            } else {
                ((u16*)outv)[(size_t)row0 * O + col] = f2bf(v0);
                ((u16*)outv)[(size_t)row1 * O + col] = f2bf(v1);
            }
        }
    }
}

// ------- fallback fused kernel (ws too small for split path) ---------------

template <int O, bool RELU, bool RES, bool OUT_F32>
__global__ __launch_bounds__(256) void fused_gemm_kernel(const int* __restrict__ row_ptr,
                                                         const int2* __restrict__ ecw,
                                                         const u16* __restrict__ H,
                                                         const u16* __restrict__ T1,
                                                         const u16* __restrict__ Wp,
                                                         const float* __restrict__ bias,
                                                         void* __restrict__ outv) {
    __shared__ __align__(16) u16 sT[16 * LDS_PITCH];
    int wid = threadIdx.x >> 6;
    int lane = threadIdx.x & 63;
    int g = lane >> 4, f = lane & 15;
    int m0 = blockIdx.x * 16;

    {
        float acc[4][8];
        gather4(row_ptr, ecw, T1, m0 + wid * 4, lane, g, f, acc);
        if (g == 0) {
#pragma unroll
            for (int y = 0; y < 4; ++y) {
                u16 tmp[8];
#pragma unroll
                for (int j = 0; j < 8; ++j) tmp[j] = f2bf(acc[y][j]);
                *(bf16x8*)(sT + (wid * 4 + y) * LDS_PITCH + f * 8) = *(const bf16x8*)tmp;
            }
        }
    }
    __syncthreads();

    int r = f, q = g;
    constexpr int NT = O / 16;
    constexpr int NW = NT / 4;
    f32x4 acc[NW];
#pragma unroll
    for (int t = 0; t < NW; ++t) acc[t] = (f32x4){0.f, 0.f, 0.f, 0.f};

#pragma unroll
    for (int kk = 0; kk < 12; ++kk) {
        bf16x8 af;
        if (kk < 4)
            af = *(const bf16x8*)(H + (size_t)(m0 + r) * FEAT + kk * 32 + q * 8);
        else if (kk < 8)
            af = *(const bf16x8*)(T1 + (size_t)(m0 + r) * FEAT + (kk - 4) * 32 + q * 8);
        else
            af = *(const bf16x8*)(sT + r * LDS_PITCH + (kk - 8) * 32 + q * 8);
#pragma unroll
        for (int t = 0; t < NW; ++t) {
            int ot = wid * NW + t;
            bf16x8 bfr = *(const bf16x8*)(Wp + (size_t)(ot * 16 + r) * 384 + kk * 32 + q * 8);
            acc[t] = __builtin_amdgcn_mfma_f32_16x16x32_bf16(af, bfr, acc[t], 0, 0, 0);
        }
    }

#pragma unroll
    for (int t = 0; t < NW; ++t) {
        int col = (wid * NW + t) * 16 + r;
        float bv = bias[col];
#pragma unroll
        for (int i = 0; i < 4; ++i) {
            int row = m0 + q * 4 + i;
            float v = acc[t][i] + bv;
            if (RES)  v += bf2f(H[(size_t)row * FEAT + col]);
            if (RELU) v = fmaxf(v, 0.f);
            if (OUT_F32) ((float*)outv)[(size_t)row * O + col] = v;
            else         ((u16*)outv)[(size_t)row * O + col] = f2bf(v);
        }
    }
}

// ---------------- launcher ----------------

static inline size_t align_up(size_t x) { return (x + 255) & ~(size_t)255; }

extern "C" void kernel_launch(void* const* d_in, const int* in_sizes, int n_in,
                              void* d_out, int out_size, void* d_ws, size_t ws_size,
                              hipStream_t stream) {
    const float* x     = (const float*)d_in[0];
    const int*   ei    = (const int*)d_in[1];
    const float* ew    = (const float*)d_in[2];
    const float* W_in  = (const float*)d_in[3];
    const float* b_in  = (const float*)d_in[4];
    const float* W_h1  = (const float*)d_in[5];
    const float* b_h1  = (const float*)d_in[6];
    const float* W_h2  = (const float*)d_in[7];
    const float* b_h2  = (const float*)d_in[8];
    const float* W_out = (const float*)d_in[9];
    const float* b_out = (const float*)d_in[10];

    const int* rows = ei;
    const int* cols = ei + N_EDGES;

    // workspace layout
    char* w = (char*)d_ws;
    size_t off = 0;
    int* counts = (int*)(w + off);            off = align_up(off + (size_t)N_NODES * 4);   // fallback fill
    int* row_ptr= (int*)(w + off);            off = align_up(off + (size_t)(N_NODES + 1) * 4);
    int* bsum   = (int*)(w + off);            off = align_up(off + 512 * 4);               // NBKT+1 fits
    int2* ecw   = (int2*)(w + off);           off = align_up(off + (size_t)N_EDGES * 8);
    u16* t1     = (u16*)(w + off);            off = align_up(off + (size_t)N_NODES * FEAT * 2);
    u16* h      = (u16*)(w + off);            off = align_up(off + (size_t)N_NODES * FEAT * 2);
    u16* Wp_in  = (u16*)(w + off);            off = align_up(off + (size_t)128 * 384 * 2);
    u16* Wp_h1  = (u16*)(w + off);            off = align_up(off + (size_t)128 * 384 * 2);
    u16* Wp_h2  = (u16*)(w + off);            off = align_up(off + (size_t)128 * 384 * 2);
    u16* Wp_out = (u16*)(w + off);            off = align_up(off + (size_t)64 * 384 * 2);
    // split path: s2 buffer (doubles as ebuf during CSR build), fragment-packed
    // weights (3 hidden K=384 + layer-4 K=128 pair), deterministic CSR counters
    u16* s2     = (u16*)(w + off);            size_t off2 = align_up(off + (size_t)N_NODES * FEAT * 2);
    u16* W2_in  = (u16*)(w + off2);           off2 = align_up(off2 + (size_t)128 * 384 * 2);
    u16* W2_h1  = (u16*)(w + off2);           off2 = align_up(off2 + (size_t)128 * 384 * 2);
    u16* W2_h2  = (u16*)(w + off2);           off2 = align_up(off2 + (size_t)128 * 384 * 2);
    u16* P_ab   = (u16*)(w + off2);           off2 = align_up(off2 + (size_t)2048 * 8 * 2);
    u16* P_f    = (u16*)(w + off2);           off2 = align_up(off2 + (size_t)1024 * 8 * 2);
    int* pcnt   = (int*)(w + off2);           off2 = align_up(off2 + (size_t)NBLK * NBKT * 4);
    int* gtot   = (int*)(w + off2);           off2 = align_up(off2 + (size_t)NBKT * 4);
    const bool use_split = (ws_size >= off2);
    static_assert((size_t)N_EDGES * 8 <= (size_t)N_NODES * FEAT * 2, "ebuf exceeds s2");

    cvt_kernel<<<(N_NODES * FEAT / 4 + 255) / 256, 256, 0, stream>>>(x, h);

    const int grid16 = N_NODES / 16;         // 6250 blocks (fallback)
    const int grid32 = N_NODES / 32;         // 3125 blocks: 32-row gemm tiles
    const int grid1  = N_NODES * 64 / 256;   // 25000 blocks: 1 row per wave

    if (use_split) {
        // CSR build v4: deterministic, zero global atomics, write-merged
        int2* ebuf = (int2*)s2;
        csr_passA_kernel<<<NBLK, 256, 0, stream>>>(rows, pcnt);
        csr_scanP_kernel<<<NBKT, 256, 0, stream>>>(pcnt, gtot);
        csr_scanG_kernel<<<1, 512, 0, stream>>>(gtot, bsum, row_ptr);
        csr_passB_kernel<<<NBLK, 256, 0, stream>>>(rows, cols, ew, pcnt, bsum, ebuf);
        csr_finalize_kernel<<<NBKT, 256, 0, stream>>>(bsum, ebuf, row_ptr, ecw);

        prep_w2_all_kernel<<<(18432 + 255) / 256, 256, 0, stream>>>(
            W_in, W_h1, W_h2, W2_in, W2_h1, W2_h2);
        prep_w4_kernel<<<(3072 + 255) / 256, 256, 0, stream>>>(W_out, P_ab, P_f);

        // Layers 1-3: spmm pair + 8-wave prefetched gemm
        spmm1_kernel<<<grid1, 256, 0, stream>>>(row_ptr, ecw, h, t1);
        spmm1_kernel<<<grid1, 256, 0, stream>>>(row_ptr, ecw, t1, s2);
        gemm8_kernel<true, false><<<grid32, 512, 0, stream>>>(h, t1, s2, W2_in, b_in, h);

        spmm1_kernel<<<grid1, 256, 0, stream>>>(row_ptr, ecw, h, t1);
        spmm1_kernel<<<grid1, 256, 0, stream>>>(row_ptr, ecw, t1, s2);
        gemm8_kernel<true, true><<<grid32, 512, 0, stream>>>(h, t1, s2, W2_h1, b_h1, h);

        spmm1_kernel<<<grid1, 256, 0, stream>>>(row_ptr, ecw, h, t1);
        spmm1_kernel<<<grid1, 256, 0, stream>>>(row_ptr, ecw, t1, s2);
        gemm8_kernel<true, true><<<grid32, 512, 0, stream>>>(h, t1, s2, W2_h2, b_h2, h);

        // Layer 4 (O=64) via associativity: gathers run 64-wide (1 line/edge)
        //   ab = h @ [W1o | 2*W2o]           (N x 128, bf16, into t1)
        //   d  = ab[:,0:64] + S*ab[:,64:128] (N x 64, into s2)
        //   e  = S*d                         (N x 64, into s2 + N*64)
        //   out = h @ (W0o - W2o) + e + b    (f32)
        {
            u16* ab = t1;
            u16* dbuf = s2;
            u16* ev = s2 + (size_t)N_NODES * 64;
            gemm1p_kernel<128, false, false, false><<<grid32, 256, 0, stream>>>(
                h, P_ab, nullptr, nullptr, ab);
            spmm64_kernel<true><<<grid1, 256, 0, stream>>>(
                row_ptr, ecw, ab + 64, 128, ab, 128, dbuf, 64);
            spmm64_kernel<false><<<grid1, 256, 0, stream>>>(
                row_ptr, ecw, dbuf, 64, nullptr, 0, ev, 64);
            gemm1p_kernel<64, true, true, true><<<grid32, 256, 0, stream>>>(
                h, P_f, ev, b_out, d_out);
        }
    } else {
        // fallback: legacy CSR build + fused path
        hipMemsetAsync(counts, 0, (size_t)N_NODES * 4, stream);
        hist_kernel<<<N_EDGES / 256, 256, 0, stream>>>(rows, counts);
        reduce_counts_kernel<<<NB_SCAN, 256, 0, stream>>>(counts, bsum);
        scan_bsums_kernel<<<1, 512, 0, stream>>>(bsum, row_ptr);
        write_rowptr_kernel<<<NB_SCAN, 256, 0, stream>>>(counts, bsum, row_ptr);
        scatter_kernel<<<N_EDGES / 256, 256, 0, stream>>>(rows, cols, ew, row_ptr, counts, ecw);

        prep_w_kernel<<<(128 * 384 + 255) / 256, 256, 0, stream>>>(W_in, Wp_in, 128);
        prep_w_kernel<<<(128 * 384 + 255) / 256, 256, 0, stream>>>(W_h1, Wp_h1, 128);
        prep_w_kernel<<<(128 * 384 + 255) / 256, 256, 0, stream>>>(W_h2, Wp_h2, 128);
        prep_w_kernel<<<(64 * 384 + 255) / 256, 256, 0, stream>>>(W_out, Wp_out, 64);

        spmm_kernel<<<grid16, 256, 0, stream>>>(row_ptr, ecw, h, t1);
        fused_gemm_kernel<128, true, false, false><<<grid16, 256, 0, stream>>>(
            row_ptr, ecw, h, t1, Wp_in, b_in, h);
        spmm_kernel<<<grid16, 256, 0, stream>>>(row_ptr, ecw, h, t1);
        fused_gemm_kernel<128, true, true, false><<<grid16, 256, 0, stream>>>(
            row_ptr, ecw, h, t1, Wp_h1, b_h1, h);
        spmm_kernel<<<grid16, 256, 0, stream>>>(row_ptr, ecw, h, t1);
        fused_gemm_kernel<128, true, true, false><<<grid16, 256, 0, stream>>>(
            row_ptr, ecw, h, t1, Wp_h2, b_h2, h);
        spmm_kernel<<<grid16, 256, 0, stream>>>(row_ptr, ecw, h, t1);
        fused_gemm_kernel<64, false, false, true><<<grid16, 256, 0, stream>>>(
            row_ptr, ecw, h, t1, Wp_out, b_out, d_out);
    }
}